// Round 2
// 249.498 us; speedup vs baseline: 1.0092x; 1.0092x over previous
//
#include <hip/hip_runtime.h>
#include <hip/hip_bf16.h>

#define LL 512
#define DD 1024
#define HH 8
#define DKK 128
#define QQ 256
#define CCC 128
#define TTT 128
#define RR 50
#define FFF 4096
#define KLD 576          // Kh rows per head: 512 keys + 50 embk + 12 ltabs + 2 pad
#define SLD 576          // (kept for workspace layout arithmetic)

typedef __attribute__((ext_vector_type(8))) short short8;
typedef __attribute__((ext_vector_type(4))) float float4v;

__device__ __forceinline__ unsigned short f2bu(float f) {
  __hip_bfloat16 h = __float2bfloat16(f);
  unsigned short u; __builtin_memcpy(&u, &h, 2); return u;
}
__device__ __forceinline__ float b2f(unsigned short u) {
  unsigned int v = ((unsigned int)u) << 16;
  float f; __builtin_memcpy(&f, &v, 4); return f;
}
__device__ __forceinline__ int4 cvt8(float4 x, float4 y) {
  int4 o;
  o.x = (int)f2bu(x.x) | ((int)f2bu(x.y) << 16);
  o.y = (int)f2bu(x.z) | ((int)f2bu(x.w) << 16);
  o.z = (int)f2bu(y.x) | ((int)f2bu(y.y) << 16);
  o.w = (int)f2bu(y.z) | ((int)f2bu(y.w) << 16);
  return o;
}

// barrier draining only LDS (lgkmcnt(0)); global loads stay in flight.
__device__ __forceinline__ void lds_barrier() {
  __builtin_amdgcn_sched_barrier(0);
  __builtin_amdgcn_s_waitcnt(0xC07F);
  __builtin_amdgcn_s_barrier();
  __builtin_amdgcn_sched_barrier(0);
}

// explicit-scalar load/store macros: no arrays, no pointer params -> no scratch.
#define LOADSET(A0,A1,B0,B1,F0,F1,F2,F3,itv) { int k0v = (itv) << 6;          \
  A0 = *(const int4*)(Az + (size_t)(bm + r)*lda + k0v + gc*8);                \
  A1 = *(const int4*)(Az + (size_t)(bm + 32 + r)*lda + k0v + gc*8);           \
  if constexpr (!CONVB) {                                                     \
    B0 = *(const int4*)(Bz16 + (size_t)(bnb + r)*ldb + k0v + gc*8);           \
    if constexpr (NB > 1)                                                     \
      B1 = *(const int4*)(Bz16 + (size_t)(bnb + 32 + r)*ldb + k0v + gc*8);    \
  } else {                                                                    \
    F0 = *(const float4*)(Bz32 + (size_t)(bnb + r)*ldb + k0v + gc*8);         \
    F1 = *(const float4*)(Bz32 + (size_t)(bnb + r)*ldb + k0v + gc*8 + 4);     \
    if constexpr (NB > 1) {                                                   \
      F2 = *(const float4*)(Bz32 + (size_t)(bnb + 32 + r)*ldb + k0v + gc*8);  \
      F3 = *(const float4*)(Bz32 + (size_t)(bnb + 32 + r)*ldb + k0v + gc*8 + 4); } } }

#define STORESET2(basep,A0,A1,B0,B1,F0,F1,F2,F3) {                            \
  char* bse = (basep);                                                        \
  *(int4*)(bse + r*128 + sl*16) = A0;                                         \
  *(int4*)(bse + (32 + r)*128 + sl*16) = A1;                                  \
  if constexpr (!CONVB) {                                                     \
    *(int4*)(bse + ABYTES + r*128 + sl*16) = B0;                              \
    if constexpr (NB > 1)                                                     \
      *(int4*)(bse + ABYTES + (32 + r)*128 + sl*16) = B1;                     \
  } else {                                                                    \
    *(int4*)(bse + ABYTES + r*128 + sl*16) = cvt8(F0, F1);                    \
    if constexpr (NB > 1)                                                     \
      *(int4*)(bse + ABYTES + (32 + r)*128 + sl*16) = cvt8(F2, F3); } }

// ---------------- kprep: fill Kh rows 512..575 (embk + l-tables, bf16) ------
__global__ __launch_bounds__(256) void kprep_kernel(
    const float* __restrict__ embk,
    const float* __restrict__ lqc, const float* __restrict__ lqt,
    const float* __restrict__ lcq, const float* __restrict__ ltq,
    unsigned short* __restrict__ Kh)
{
  int g = blockIdx.x*256 + threadIdx.x;       // 8 heads * 64 rows * 128
  if (g >= 8*64*128) return;
  int d = g & 127, rr = (g >> 7) & 63, h = g >> 13;
  float v = 0.f;
  if (rr < 50) v = embk[rr*128 + d];
  else if (rr < 62) {
    int u = rr - 50; int tb = u/3, f = u - tb*3;
    const float* tab = (tb==0) ? lqc : (tb==1) ? lqt : (tb==2) ? lcq : ltq;
    v = tab[f*128 + d];
  }
  Kh[((size_t)h*KLD + 512 + rr)*DKK + d] = f2bu(v);
}

// ---------------- LayerNorm: fp32 in, bf16 out ----------------
__global__ __launch_bounds__(256) void ln_bf16_kernel(const float* __restrict__ x,
    const float* __restrict__ g, const float* __restrict__ b,
    unsigned short* __restrict__ y)
{
  int row = blockIdx.x, t = threadIdx.x;
  const float4 xv = ((const float4*)(x + row*DD))[t];
  float s  = xv.x+xv.y+xv.z+xv.w;
  float ss = xv.x*xv.x+xv.y*xv.y+xv.z*xv.z+xv.w*xv.w;
  __shared__ float rs[256], rss[256];
  rs[t]=s; rss[t]=ss; __syncthreads();
  for (int st=128; st>0; st>>=1){ if (t<st){ rs[t]+=rs[t+st]; rss[t]+=rss[t+st]; } __syncthreads(); }
  float mean = rs[0] * (1.0f/DD);
  float var  = rss[0]*(1.0f/DD) - mean*mean;
  float inv  = rsqrtf(var + 1e-5f);
  float4 gv = ((const float4*)g)[t], bv = ((const float4*)b)[t];
  ushort4 ov;
  ov.x = f2bu((xv.x-mean)*inv*gv.x + bv.x);
  ov.y = f2bu((xv.y-mean)*inv*gv.y + bv.y);
  ov.z = f2bu((xv.z-mean)*inv*gv.z + bv.z);
  ov.w = f2bu((xv.w-mean)*inv*gv.w + bv.w);
  ((ushort4*)(y + row*DD))[t] = ov;
}

// ---------------- LayerNorm + out += b2 (split-K init) ----------------
__global__ __launch_bounds__(256) void ln_bf16_addb_kernel(float* __restrict__ x,
    const float* __restrict__ g, const float* __restrict__ b,
    const float* __restrict__ b2, unsigned short* __restrict__ y)
{
  int row = blockIdx.x, t = threadIdx.x;
  const float4 xv = ((const float4*)(x + row*DD))[t];
  float s  = xv.x+xv.y+xv.z+xv.w;
  float ss = xv.x*xv.x+xv.y*xv.y+xv.z*xv.z+xv.w*xv.w;
  __shared__ float rs[256], rss[256];
  rs[t]=s; rss[t]=ss; __syncthreads();
  for (int st=128; st>0; st>>=1){ if (t<st){ rs[t]+=rs[t+st]; rss[t]+=rss[t+st]; } __syncthreads(); }
  float mean = rs[0] * (1.0f/DD);
  float var  = rss[0]*(1.0f/DD) - mean*mean;
  float inv  = rsqrtf(var + 1e-5f);
  float4 gv = ((const float4*)g)[t], bv = ((const float4*)b)[t];
  ushort4 ov;
  ov.x = f2bu((xv.x-mean)*inv*gv.x + bv.x);
  ov.y = f2bu((xv.y-mean)*inv*gv.y + bv.y);
  ov.z = f2bu((xv.z-mean)*inv*gv.z + bv.z);
  ov.w = f2bu((xv.w-mean)*inv*gv.w + bv.w);
  ((ushort4*)(y + row*DD))[t] = ov;
  float4 b2v = ((const float4*)b2)[t];
  float4 nx; nx.x = xv.x+b2v.x; nx.y = xv.y+b2v.y; nx.z = xv.z+b2v.z; nx.w = xv.w+b2v.w;
  ((float4*)(x + row*DD))[t] = nx;
}

// ======== VGPR-staged pipelined bf16 MFMA GEMM; DEPTH = prefetch depth ======
template<int BN, int DEPTH, int CONVB, int ZK, int OUT_BF16, int RELU, int HAS_SRC, int HAS_BIAS>
__global__ __launch_bounds__(256) void gemm_pl(
    const unsigned short* __restrict__ A, int lda, size_t sAz,
    const void* __restrict__ Bv, int ldb, size_t sBz,
    const float* __restrict__ bias,
    const float* __restrict__ src, int ldsrc, size_t sSz,
    void* __restrict__ Cv, int ldc, size_t sCz,
    int K)
{
  constexpr int BM = 64;
  constexpr int WM = 32, WN = BN/2, FM = 2, FN = WN/16;
  constexpr int NB = BN/32;
  constexpr int ABYTES = BM*128, TILE = ABYTES + BN*128;
  __shared__ char lds[2*TILE];
  int t = threadIdx.x, w = t >> 6, l = t & 63;
  size_t z = blockIdx.z;
  const unsigned short* Az = A + z*sAz;
  const unsigned short* Bz16 = (const unsigned short*)Bv + (CONVB ? 0 : z*sBz);
  const float*          Bz32 = (const float*)Bv + (CONVB ? z*sBz : 0);
  int bm = blockIdx.y*BM, bn = blockIdx.x*BN;
  int bnb = bn;
  int wm = (w>>1)*WM, wn = (w&1)*WN;

  float4v acc[FM][FN];
  #pragma unroll
  for (int m=0;m<FM;++m)
    #pragma unroll
    for (int n=0;n<FN;++n) acc[m][n] = (float4v){0.f,0.f,0.f,0.f};

  int r = t >> 3, sl = t & 7;
  int gc = sl ^ (r & 7);
  int quad = l >> 4, lrow = l & 15;
  const int nit = K >> 6;   // DEPTH==2: nit even; DEPTH==4: nit % 4 == 0

  int4 Aa0, Aa1, Ab0, Ab1;  float4 Af0, Af1, Af2, Af3;
  int4 Ba0, Ba1, Bb0, Bb1;  float4 Bf0, Bf1, Bf2, Bf3;
  int4 Ca0, Ca1, Cb0, Cb1;  float4 Cf0, Cf1, Cf2, Cf3;
  int4 Da0, Da1, Db0, Db1;  float4 Df0, Df1, Df2, Df3;

  auto compute = [&](const char* base) {
    const char* ab = base;
    const char* bb = base + ABYTES;
    #pragma unroll
    for (int step=0; step<2; ++step) {
      int c = step*4 + quad;
      short8 af[FM], bf[FN];
      #pragma unroll
      for (int m=0;m<FM;++m) {
        int Rw = wm + m*16 + lrow;
        af[m] = *(const short8*)(ab + Rw*128 + ((c ^ (Rw & 7))*16));
      }
      #pragma unroll
      for (int n=0;n<FN;++n) {
        int Rw = wn + n*16 + lrow;
        bf[n] = *(const short8*)(bb + Rw*128 + ((c ^ (Rw & 7))*16));
      }
      #pragma unroll
      for (int m=0;m<FM;++m)
        #pragma unroll
        for (int n=0;n<FN;++n)
          acc[m][n] = __builtin_amdgcn_mfma_f32_16x16x32_bf16(af[m], bf[n], acc[m][n], 0, 0, 0);
    }
  };

  if constexpr (DEPTH == 2) {
    LOADSET(Aa0,Aa1,Ab0,Ab1,Af0,Af1,Af2,Af3, 0);
    LOADSET(Ba0,Ba1,Bb0,Bb1,Bf0,Bf1,Bf2,Bf3, 1);
    for (int it = 0; it < nit; it += 2) {
      STORESET2(lds, Aa0,Aa1,Ab0,Ab1,Af0,Af1,Af2,Af3);
      if (it + 2 < nit) LOADSET(Aa0,Aa1,Ab0,Ab1,Af0,Af1,Af2,Af3, it+2);
      lds_barrier();
      compute(lds);
      STORESET2(lds + TILE, Ba0,Ba1,Bb0,Bb1,Bf0,Bf1,Bf2,Bf3);
      if (it + 3 < nit) LOADSET(Ba0,Ba1,Bb0,Bb1,Bf0,Bf1,Bf2,Bf3, it+3);
      lds_barrier();
      compute(lds + TILE);
    }
  } else {
    LOADSET(Aa0,Aa1,Ab0,Ab1,Af0,Af1,Af2,Af3, 0);
    LOADSET(Ba0,Ba1,Bb0,Bb1,Bf0,Bf1,Bf2,Bf3, 1);
    LOADSET(Ca0,Ca1,Cb0,Cb1,Cf0,Cf1,Cf2,Cf3, 2);
    LOADSET(Da0,Da1,Db0,Db1,Df0,Df1,Df2,Df3, 3);
    for (int it = 0; it < nit; it += 4) {
      STORESET2(lds, Aa0,Aa1,Ab0,Ab1,Af0,Af1,Af2,Af3);
      if (it + 4 < nit) LOADSET(Aa0,Aa1,Ab0,Ab1,Af0,Af1,Af2,Af3, it+4);
      lds_barrier();
      compute(lds);
      STORESET2(lds + TILE, Ba0,Ba1,Bb0,Bb1,Bf0,Bf1,Bf2,Bf3);
      if (it + 5 < nit) LOADSET(Ba0,Ba1,Bb0,Bb1,Bf0,Bf1,Bf2,Bf3, it+5);
      lds_barrier();
      compute(lds + TILE);
      STORESET2(lds, Ca0,Ca1,Cb0,Cb1,Cf0,Cf1,Cf2,Cf3);
      if (it + 6 < nit) LOADSET(Ca0,Ca1,Cb0,Cb1,Cf0,Cf1,Cf2,Cf3, it+6);
      lds_barrier();
      compute(lds);
      STORESET2(lds + TILE, Da0,Da1,Db0,Db1,Df0,Df1,Df2,Df3);
      if (it + 7 < nit) LOADSET(Da0,Da1,Db0,Db1,Df0,Df1,Df2,Df3, it+7);
      lds_barrier();
      compute(lds + TILE);
    }
  }

  #pragma unroll
  for (int m=0;m<FM;++m)
    #pragma unroll
    for (int n=0;n<FN;++n)
      #pragma unroll
      for (int rg=0;rg<4;++rg) {
        int row = bm + wm + m*16 + quad*4 + rg;
        int col = bn + wn + n*16 + lrow;
        float vv = acc[m][n][rg];
        if (ZK) {
          atomicAdd(&((float*)Cv)[(size_t)row*ldc + col], vv);
        } else {
          if (HAS_BIAS) vv += bias[col];
          if (HAS_SRC)  vv += src[z*sSz + (size_t)row*ldsrc + col];
          if (RELU) vv = fmaxf(vv, 0.f);
          if (OUT_BF16) ((unsigned short*)Cv)[z*sCz + (size_t)row*ldc + col] = f2bu(vv);
          else          ((float*)Cv)[z*sCz + (size_t)row*ldc + col] = vv;
        }
      }
}

// ---------------- QKV GEMM: fp32 weights direct, DEPTH4, head-scatter -------
__global__ __launch_bounds__(256) void gemm_qkv_pl(
    const unsigned short* __restrict__ A,
    const float* __restrict__ Wq, const float* __restrict__ Wk,
    const float* __restrict__ Wv,
    const float* __restrict__ bq, const float* __restrict__ bk,
    const float* __restrict__ bv,
    unsigned short* __restrict__ Qh, unsigned short* __restrict__ Kh,
    unsigned short* __restrict__ Vt)
{
  constexpr int BN = 64, CONVB = 1;
  constexpr int WM = 32, WN = 32, FM = 2, FN = 2;
  constexpr int NB = 2;
  constexpr int ABYTES = 64*128, TILE = ABYTES + BN*128;
  __shared__ char lds[2*TILE];
  int t = threadIdx.x, w = t >> 6, l = t & 63;
  int bm = blockIdx.y*64, bn = blockIdx.x*BN;
  int wm = (w>>1)*WM, wn = (w&1)*WN;
  const int lda = DD, ldb = DD, nit = DD >> 6;   // 16
  const unsigned short* Az = A;
  int part0 = bn >> 10;
  const float* Bz32 = (part0==0 ? Wq : part0==1 ? Wk : Wv) + (size_t)(bn & 1023)*DD;
  const unsigned short* Bz16 = nullptr; (void)Bz16;
  int bnb = 0;

  float4v acc[FM][FN];
  #pragma unroll
  for (int m=0;m<FM;++m)
    #pragma unroll
    for (int n=0;n<FN;++n) acc[m][n] = (float4v){0.f,0.f,0.f,0.f};

  int r = t >> 3, sl = t & 7;
  int gc = sl ^ (r & 7);
  int quad = l >> 4, lrow = l & 15;

  int4 Aa0, Aa1, Ab0, Ab1;  float4 Af0, Af1, Af2, Af3;
  int4 Ba0, Ba1, Bb0, Bb1;  float4 Bf0, Bf1, Bf2, Bf3;
  int4 Ca0, Ca1, Cb0, Cb1;  float4 Cf0, Cf1, Cf2, Cf3;
  int4 Da0, Da1, Db0, Db1;  float4 Df0, Df1, Df2, Df3;

  auto compute = [&](const char* base) {
    const char* ab = base;
    const char* bb = base + ABYTES;
    #pragma unroll
    for (int step=0; step<2; ++step) {
      int c = step*4 + quad;
      short8 af[FM], bf[FN];
      #pragma unroll
      for (int m=0;m<FM;++m) {
        int Rw = wm + m*16 + lrow;
        af[m] = *(const short8*)(ab + Rw*128 + ((c ^ (Rw & 7))*16));
      }
      #pragma unroll
      for (int n=0;n<FN;++n) {
        int Rw = wn + n*16 + lrow;
        bf[n] = *(const short8*)(bb + Rw*128 + ((c ^ (Rw & 7))*16));
      }
      #pragma unroll
      for (int m=0;m<FM;++m)
        #pragma unroll
        for (int n=0;n<FN;++n)
          acc[m][n] = __builtin_amdgcn_mfma_f32_16x16x32_bf16(af[m], bf[n], acc[m][n], 0, 0, 0);
    }
  };

  LOADSET(Aa0,Aa1,Ab0,Ab1,Af0,Af1,Af2,Af3, 0);
  LOADSET(Ba0,Ba1,Bb0,Bb1,Bf0,Bf1,Bf2,Bf3, 1);
  LOADSET(Ca0,Ca1,Cb0,Cb1,Cf0,Cf1,Cf2,Cf3, 2);
  LOADSET(Da0,Da1,Db0,Db1,Df0,Df1,Df2,Df3, 3);
  for (int it = 0; it < nit; it += 4) {
    STORESET2(lds, Aa0,Aa1,Ab0,Ab1,Af0,Af1,Af2,Af3);
    if (it + 4 < nit) LOADSET(Aa0,Aa1,Ab0,Ab1,Af0,Af1,Af2,Af3, it+4);
    lds_barrier();
    compute(lds);
    STORESET2(lds + TILE, Ba0,Ba1,Bb0,Bb1,Bf0,Bf1,Bf2,Bf3);
    if (it + 5 < nit) LOADSET(Ba0,Ba1,Bb0,Bb1,Bf0,Bf1,Bf2,Bf3, it+5);
    lds_barrier();
    compute(lds + TILE);
    STORESET2(lds, Ca0,Ca1,Cb0,Cb1,Cf0,Cf1,Cf2,Cf3);
    if (it + 6 < nit) LOADSET(Ca0,Ca1,Cb0,Cb1,Cf0,Cf1,Cf2,Cf3, it+6);
    lds_barrier();
    compute(lds);
    STORESET2(lds + TILE, Da0,Da1,Db0,Db1,Df0,Df1,Df2,Df3);
    if (it + 7 < nit) LOADSET(Da0,Da1,Db0,Db1,Df0,Df1,Df2,Df3, it+7);
    lds_barrier();
    compute(lds + TILE);
  }

  #pragma unroll
  for (int m=0;m<FM;++m)
    #pragma unroll
    for (int n=0;n<FN;++n)
      #pragma unroll
      for (int rg=0;rg<4;++rg) {
        int row = bm + wm + m*16 + quad*4 + rg;
        int col = bn + wn + n*16 + lrow;
        int part = col >> 10, hh = (col >> 7) & 7, d = col & 127;
        const float* bp = (part==0) ? bq : (part==1) ? bk : bv;
        float vv = acc[m][n][rg] + bp[col & 1023];
        unsigned short o = f2bu(vv);
        if (part == 0)      Qh[((size_t)hh*LL + row)*DKK + d] = o;
        else if (part == 1) Kh[((size_t)hh*KLD + row)*DKK + d] = o;
        else                Vt[((size_t)hh*DKK + d)*LL + row] = o;
      }
}

// ======== fused attention: scores + softmax + pw/pf + PV + o2, per (h, 16-row i-tile) ========
// LDS map (bytes), region overlap by phase:
//   [0      , 4352 )  Qt  [16][136] bf16   (phase 1)         }  overlapped by
//   [4352   , 21760)  Kt  [64][136] bf16   (phase 1)         }  P [16][520] bf16 @0 (phase 2/3)
//   [21760  , 59136)  S   [16][584] f32    (phase 1/2)       -> V [128][72] bf16 (phase 3)
//   [59136  , 62464)  pws [16][52]  f32
//   [62464  , 62720)  pf1 [16][4]   f32
//   [62720  , 62976)  pf2 [16][4]   f32
#define AT_QROWB 272
#define AT_KROWB 272
#define AT_SROW  584
#define AT_PROWB 1040
#define AT_VROWB 144
#define AT_OFF_KT 4352
#define AT_OFF_S  21760
#define AT_OFF_V  21760
#define AT_OFF_PW 59136
#define AT_OFF_PF1 62464
#define AT_OFF_PF2 62720
#define AT_LDS 62976

__global__ __launch_bounds__(256) void attn_fused(
    const unsigned short* __restrict__ Qh, const unsigned short* __restrict__ Kh,
    const unsigned short* __restrict__ Vt,
    const float* __restrict__ qcr, const float* __restrict__ cqr,
    const float* __restrict__ qtr, const float* __restrict__ tqr,
    const int* __restrict__ ct, const int* __restrict__ pred,
    const int* __restrict__ mask,
    const float* __restrict__ embv, const float* __restrict__ lqc_v,
    const float* __restrict__ lcq_v, const float* __restrict__ lqt_v,
    const float* __restrict__ ltq_v,
    unsigned short* __restrict__ obuf)
{
  __shared__ __align__(16) char lds[AT_LDS];
  const int t = threadIdx.x;
  const int w = t >> 6, l = t & 63, quad = l >> 4, lrow = l & 15;
  const int i0 = blockIdx.x * 16, h = blockIdx.y;

  // zero pws/pf region (960 floats = 3840 B)
  for (int k2 = t; k2 < 960; k2 += 256) ((float*)(lds + AT_OFF_PW))[k2] = 0.f;

  // stage Q tile [16][128] once
  {
    int qr = t >> 4, qc = t & 15;
    *(int4*)(lds + qr*AT_QROWB + qc*16) =
        *(const int4*)(Qh + ((size_t)h*LL + i0 + qr)*DKK + qc*8);
  }

  const int kr = t >> 4, kc = t & 15;       // K staging: 4 rows/thread
  int4 kv0, kv1, kv2, kv3;
#define AT_LOADK(jtv) { size_t kb = (size_t)h*KLD + (size_t)(jtv)*64 + kr;     \
    kv0 = *(const int4*)(Kh + (kb     )*DKK + kc*8);                           \
    kv1 = *(const int4*)(Kh + (kb + 16)*DKK + kc*8);                           \
    kv2 = *(const int4*)(Kh + (kb + 32)*DKK + kc*8);                           \
    kv3 = *(const int4*)(Kh + (kb + 48)*DKK + kc*8); }
#define AT_STOREK() {                                                          \
    *(int4*)(lds + AT_OFF_KT + (kr     )*AT_KROWB + kc*16) = kv0;              \
    *(int4*)(lds + AT_OFF_KT + (kr + 16)*AT_KROWB + kc*16) = kv1;              \
    *(int4*)(lds + AT_OFF_KT + (kr + 32)*AT_KROWB + kc*16) = kv2;              \
    *(int4*)(lds + AT_OFF_KT + (kr + 48)*AT_KROWB + kc*16) = kv3; }

  // ---- phase 1: S[16][576] = Q @ Kh^T (incl. qe/lq dot columns 512..575) ----
  AT_LOADK(0);
  for (int jt = 0; jt < 9; ++jt) {
    lds_barrier();                 // prior compute done reading Kt
    AT_STOREK();
    if (jt + 1 < 9) AT_LOADK(jt + 1);
    lds_barrier();                 // Kt (and Qt, first iter) visible
    float4v acc = (float4v){0.f,0.f,0.f,0.f};
    #pragma unroll
    for (int kk = 0; kk < 4; ++kk) {
      int c = kk*4 + quad;
      short8 af = *(const short8*)(lds + lrow*AT_QROWB + c*16);
      short8 bf = *(const short8*)(lds + AT_OFF_KT + (w*16 + lrow)*AT_KROWB + c*16);
      acc = __builtin_amdgcn_mfma_f32_16x16x32_bf16(af, bf, acc, 0, 0, 0);
    }
    #pragma unroll
    for (int rg = 0; rg < 4; ++rg)
      ((float*)(lds + AT_OFF_S))[(quad*4 + rg)*AT_SROW + jt*64 + w*16 + lrow] = acc[rg];
  }
  lds_barrier();

  // ---- phase 2: softmax over cols 0..511, per-row (16-lane group per row) ----
  const int row = t >> 4, l16 = t & 15;
  const int i = i0 + row;
  const float* Srow = (const float*)(lds + AT_OFF_S) + row*AT_SROW;
  const int base = (i0 < QQ) ? 562 : (i0 < QQ + CCC) ? 568 : 571;
  const float lq1a = Srow[base], lq1b = Srow[base+1], lq1c = Srow[base+2];
  const float lq2a = Srow[565], lq2b = Srow[566], lq2c = Srow[567];

  // prefetch first V tile during softmax
  const int vr = t >> 3, vc = t & 7;        // V staging: 4 d-rows/thread
  int4 vv0, vv1, vv2, vv3;
#define AT_LOADV(itv) { size_t vb = (size_t)h*DKK + vr;                        \
    size_t vo = (size_t)(itv)*64 + vc*8;                                       \
    vv0 = *(const int4*)(Vt + (vb      )*LL + vo);                             \
    vv1 = *(const int4*)(Vt + (vb + 32)*LL + vo);                              \
    vv2 = *(const int4*)(Vt + (vb + 64)*LL + vo);                              \
    vv3 = *(const int4*)(Vt + (vb + 96)*LL + vo); }
#define AT_STOREV() {                                                          \
    *(int4*)(lds + AT_OFF_V + (vr     )*AT_VROWB + vc*16) = vv0;               \
    *(int4*)(lds + AT_OFF_V + (vr + 32)*AT_VROWB + vc*16) = vv1;               \
    *(int4*)(lds + AT_OFF_V + (vr + 64)*AT_VROWB + vc*16) = vv2;               \
    *(int4*)(lds + AT_OFF_V + (vr + 96)*AT_VROWB + vc*16) = vv3; }
  AT_LOADV(0);

  float sv[32];
  #pragma unroll
  for (int m = 0; m < 32; ++m) {
    int j = m*16 + l16;
    int predv = pred[i*LL + j];
    int maskv = mask[i*LL + j];
    float s = Srow[j] + Srow[512 + predv];
    if (i0 < QQ) {
      if (j < QQ) s += Srow[512];                       // default q:q (id 0)
      else if (j < QQ + CCC) {
        const float* r3 = qcr + ((size_t)i*CCC + (j - QQ))*3;
        s += r3[0]*lq1a + r3[1]*lq1b + r3[2]*lq1c;
      } else {
        const float* r3 = qtr + ((size_t)i*TTT + (j - QQ - CCC))*3;
        s += r3[0]*lq2a + r3[1]*lq2b + r3[2]*lq2c;
      }
    } else {
      if (j < QQ) {
        const float* r3 = (i < QQ + CCC) ? cqr + ((size_t)(i - QQ)*QQ + j)*3
                                         : tqr + ((size_t)(i - QQ - CCC)*QQ + j)*3;
        s += r3[0]*lq1a + r3[1]*lq1b + r3[2]*lq1c;
      } else {
        int scat2 = ct[(i - QQ)*(CCC + TTT) + (j - QQ)];
        s += Srow[512 + scat2];
      }
    }
    s *= 0.08838834764831845f;
    if (maskv == 0) s = -1e9f;
    sv[m] = s;
  }
  float mx = sv[0];
  #pragma unroll
  for (int m = 1; m < 32; ++m) mx = fmaxf(mx, sv[m]);
  #pragma unroll
  for (int off = 8; off >= 1; off >>= 1) mx = fmaxf(mx, __shfl_xor(mx, off));
  float sum = 0.f;
  #pragma unroll
  for (int m = 0; m < 32; ++m) { float e = __expf(sv[m] - mx); sv[m] = e; sum += e; }
  #pragma unroll
  for (int off = 8; off >= 1; off >>= 1) sum += __shfl_xor(sum, off);
  const float inv = 1.0f / sum;

  float f0=0.f, f1=0.f, f2=0.f, g0=0.f, g1=0.f, g2=0.f;
  #pragma unroll
  for (int m = 0; m < 32; ++m) {
    int j = m*16 + l16;
    float p = sv[m] * inv;
    *(unsigned short*)(lds + row*AT_PROWB + j*2) = f2bu(p);   // P (overlaps Qt/Kt)
    int predv = pred[i*LL + j];
    atomicAdd((float*)(lds + AT_OFF_PW) + row*52 + predv, p);
    if (i0 < QQ) {
      if (j < QQ) atomicAdd((float*)(lds + AT_OFF_PW) + row*52, p);
      else if (j < QQ + CCC) {
        const float* r3 = qcr + ((size_t)i*CCC + (j - QQ))*3;
        f0 += p*r3[0]; f1 += p*r3[1]; f2 += p*r3[2];
      } else {
        const float* r3 = qtr + ((size_t)i*TTT + (j - QQ - CCC))*3;
        g0 += p*r3[0]; g1 += p*r3[1]; g2 += p*r3[2];
      }
    } else {
      if (j < QQ) {
        const float* r3 = (i < QQ + CCC) ? cqr + ((size_t)(i - QQ)*QQ + j)*3
                                         : tqr + ((size_t)(i - QQ - CCC)*QQ + j)*3;
        f0 += p*r3[0]; f1 += p*r3[1]; f2 += p*r3[2];
      } else {
        int scat2 = ct[(i - QQ)*(CCC + TTT) + (j - QQ)];
        atomicAdd((float*)(lds + AT_OFF_PW) + row*52 + scat2, p);
      }
    }
  }
  #pragma unroll
  for (int off = 8; off >= 1; off >>= 1) {
    f0 += __shfl_xor(f0, off); f1 += __shfl_xor(f1, off); f2 += __shfl_xor(f2, off);
    g0 += __shfl_xor(g0, off); g1 += __shfl_xor(g1, off); g2 += __shfl_xor(g2, off);
  }
  if (l16 == 0) {
    float* pf1 = (float*)(lds + AT_OFF_PF1) + row*4;
    float* pf2 = (float*)(lds + AT_OFF_PF2) + row*4;
    pf1[0] = f0; pf1[1] = f1; pf1[2] = f2;
    pf2[0] = g0; pf2[1] = g1; pf2[2] = g2;
  }

  // ---- phase 3: O[16][128] = P @ V^T ----
  float4v oacc0 = (float4v){0.f,0.f,0.f,0.f};
  float4v oacc1 = (float4v){0.f,0.f,0.f,0.f};
  for (int it = 0; it < 8; ++it) {
    lds_barrier();                 // phase-2 LDS ops (it=0) / prior V reads done
    AT_STOREV();
    if (it + 1 < 8) AT_LOADV(it + 1);
    lds_barrier();
    #pragma unroll
    for (int kk = 0; kk < 2; ++kk) {
      int c = kk*4 + quad;
      short8 pa = *(const short8*)(lds + lrow*AT_PROWB + it*128 + c*16);
      short8 vf0 = *(const short8*)(lds + AT_OFF_V + (w*32 + lrow)*AT_VROWB + c*16);
      short8 vf1 = *(const short8*)(lds + AT_OFF_V + (w*32 + 16 + lrow)*AT_VROWB + c*16);
      oacc0 = __builtin_amdgcn_mfma_f32_16x16x32_bf16(pa, vf0, oacc0, 0, 0, 0);
      oacc1 = __builtin_amdgcn_mfma_f32_16x16x32_bf16(pa, vf1, oacc1, 0, 0, 0);
    }
  }

  // ---- epilogue: add pws@embv + pf@tables (the o2 term), store obuf bf16 ----
  const float* tab1 = (i0 < QQ) ? lqc_v : (i0 < QQ + CCC) ? lcq_v : ltq_v;
  const bool hasT2 = (i0 < QQ);
  const float* pws = (const float*)(lds + AT_OFF_PW);
  #pragma unroll
  for (int n = 0; n < 2; ++n) {
    int d = w*32 + n*16 + lrow;
    float a0=0.f, a1=0.f, a2=0.f, a3=0.f;
    #pragma unroll 5
    for (int rr = 0; rr < RR; ++rr) {
      float evv = embv[rr*DKK + d];
      a0 += pws[(quad*4+0)*52 + rr]*evv;
      a1 += pws[(quad*4+1)*52 + rr]*evv;
      a2 += pws[(quad*4+2)*52 + rr]*evv;
      a3 += pws[(quad*4+3)*52 + rr]*evv;
    }
    float t0 = tab1[d], t1 = tab1[DKK + d], t2 = tab1[2*DKK + d];
    float u0 = 0.f, u1 = 0.f, u2 = 0.f;
    if (hasT2) { u0 = lqt_v[d]; u1 = lqt_v[DKK + d]; u2 = lqt_v[2*DKK + d]; }
    #pragma unroll
    for (int rg = 0; rg < 4; ++rg) {
      int rw = quad*4 + rg;
      const float* pf1 = (const float*)(lds + AT_OFF_PF1) + rw*4;
      const float* pf2 = (const float*)(lds + AT_OFF_PF2) + rw*4;
      float aval = (rg==0) ? a0 : (rg==1) ? a1 : (rg==2) ? a2 : a3;
      float oval = (n==0) ? oacc0[rg] : oacc1[rg];
      float val = oval + aval
                + pf1[0]*t0 + pf1[1]*t1 + pf1[2]*t2
                + pf2[0]*u0 + pf2[1]*u1 + pf2[2]*u2;
      obuf[(size_t)(i0 + rw)*DD + h*DKK + d] = f2bu(val);
    }
  }
}

// ---------------- launch ----------------
extern "C" void kernel_launch(void* const* d_in, const int* in_sizes, int n_in,
                              void* d_out, int out_size, void* d_ws, size_t ws_size,
                              hipStream_t stream)
{
  const float* x    = (const float*)d_in[0];
  const float* qcr  = (const float*)d_in[1];
  const float* cqr  = (const float*)d_in[2];
  const float* qtr  = (const float*)d_in[3];
  const float* tqr  = (const float*)d_in[4];
  const int*   ct   = (const int*)d_in[5];
  const int*   pred = (const int*)d_in[6];
  const int*   mask = (const int*)d_in[7];
  const float* embk = (const float*)d_in[8];
  const float* embv = (const float*)d_in[9];
  const float* lqc_k = (const float*)d_in[10];
  const float* lqc_v = (const float*)d_in[11];
  const float* lcq_k = (const float*)d_in[12];
  const float* lcq_v = (const float*)d_in[13];
  const float* lqt_k = (const float*)d_in[14];
  const float* lqt_v = (const float*)d_in[15];
  const float* ltq_k = (const float*)d_in[16];
  const float* ltq_v = (const float*)d_in[17];
  const float* Wq = (const float*)d_in[18]; const float* bq = (const float*)d_in[19];
  const float* Wk = (const float*)d_in[20]; const float* bk = (const float*)d_in[21];
  const float* Wv = (const float*)d_in[22]; const float* bv = (const float*)d_in[23];
  const float* Wo = (const float*)d_in[24]; const float* bo = (const float*)d_in[25];
  const float* ln1_g = (const float*)d_in[26]; const float* ln1_b = (const float*)d_in[27];
  const float* ln2_g = (const float*)d_in[28]; const float* ln2_b = (const float*)d_in[29];
  const float* W1 = (const float*)d_in[30]; const float* b1 = (const float*)d_in[31];
  const float* W2 = (const float*)d_in[32]; const float* b2 = (const float*)d_in[33];
  float* out = (float*)d_out;

  float* wsf = (float*)d_ws;
  float* S    = wsf;                          // FFN hidden region (attention no longer uses it)
  float* o2   = S + (size_t)HH*LL*SLD;        // kept for layout stability (unused)
  unsigned short* ub = (unsigned short*)(o2 + (size_t)HH*LL*DKK);
  unsigned short* ybuf_b = ub;                        // [L,D]
  unsigned short* obuf_b = ybuf_b + LL*DD;            // [L,D]
  unsigned short* Qh     = obuf_b + LL*DD;            // [H][512][128]
  unsigned short* Kh     = Qh + (size_t)HH*LL*DKK;    // [H][576][128]
  unsigned short* Vt     = Kh + (size_t)HH*KLD*DKK;   // [H][128][512]
  unsigned short* hidden = (unsigned short*)S;        // [L][FFF] bf16

  // 1. fill Kh bias rows (independent of everything)
  kprep_kernel<<<(8*64*128 + 255)/256, 256, 0, stream>>>(
      embk, lqc_k, lqt_k, lcq_k, ltq_k, Kh);
  // 2. LN1 -> bf16
  ln_bf16_kernel<<<LL, 256, 0, stream>>>(x, ln1_g, ln1_b, ybuf_b);
  // 3. QKV GEMM (fp32 weights direct, depth-4) with head scatter
  gemm_qkv_pl<<<dim3(48, 8), 256, 0, stream>>>(ybuf_b, Wq, Wk, Wv, bq, bk, bv,
                                               Qh, Kh, Vt);
  // 4. fused attention: scores + softmax + pw/pf + PV + o2 -> obuf bf16
  attn_fused<<<dim3(32, 8), 256, 0, stream>>>(
      Qh, Kh, Vt, qcr, cqr, qtr, tqr, ct, pred, mask,
      embv, lqc_v, lcq_v, lqt_v, ltq_v, obuf_b);
  // 5. out-proj (fp32 Wo direct, depth-4) + residual(x) -> out
  gemm_pl<32,4,1,0,0,0,1,1><<<dim3(32, 8, 1), 256, 0, stream>>>(
      obuf_b, DD, 0, Wo, DD, 0, bo, x, DD, 0, out, DD, 0, DD);
  // 6. LN2 -> bf16, and out += b2 (split-K init)
  ln_bf16_addb_kernel<<<LL, 256, 0, stream>>>(out, ln2_g, ln2_b, b2, ybuf_b);
  // 7. FFN1 relu (fp32 W1 direct, depth-4) -> hidden bf16
  gemm_pl<64,4,1,0,1,1,0,1><<<dim3(64, 8, 1), 256, 0, stream>>>(
      ybuf_b, DD, 0, W1, DD, 0, b1, nullptr, 0, 0, hidden, FFF, 0, DD);
  // 8. FFN2 split-K x4 (fp32 W2 direct, depth-4), atomicAdd -> out
  gemm_pl<64,4,1,1,0,0,0,0><<<dim3(16, 8, 4), 256, 0, stream>>>(
      hidden, FFF, (size_t)1024, W2, FFF, (size_t)1024,
      nullptr, nullptr, 0, 0, out, DD, 0, 1024);
}

// Round 3
// 247.252 us; speedup vs baseline: 1.0184x; 1.0091x over previous
//
#include <hip/hip_runtime.h>
#include <hip/hip_bf16.h>

#define LL 512
#define DD 1024
#define HH 8
#define DKK 128
#define QQ 256
#define CCC 128
#define TTT 128
#define RR 50
#define FFF 4096
#define KLD 576          // Kh rows per head: 512 keys + 50 embk + 12 ltabs + 2 pad
#define SLD 576          // (kept for workspace layout arithmetic)

typedef __attribute__((ext_vector_type(8))) short short8;
typedef __attribute__((ext_vector_type(4))) float float4v;

__device__ __forceinline__ unsigned short f2bu(float f) {
  __hip_bfloat16 h = __float2bfloat16(f);
  unsigned short u; __builtin_memcpy(&u, &h, 2); return u;
}
__device__ __forceinline__ float b2f(unsigned short u) {
  unsigned int v = ((unsigned int)u) << 16;
  float f; __builtin_memcpy(&f, &v, 4); return f;
}
__device__ __forceinline__ int4 cvt8(float4 x, float4 y) {
  int4 o;
  o.x = (int)f2bu(x.x) | ((int)f2bu(x.y) << 16);
  o.y = (int)f2bu(x.z) | ((int)f2bu(x.w) << 16);
  o.z = (int)f2bu(y.x) | ((int)f2bu(y.y) << 16);
  o.w = (int)f2bu(y.z) | ((int)f2bu(y.w) << 16);
  return o;
}

// barrier draining only LDS (lgkmcnt(0)); global loads stay in flight.
__device__ __forceinline__ void lds_barrier() {
  __builtin_amdgcn_sched_barrier(0);
  __builtin_amdgcn_s_waitcnt(0xC07F);
  __builtin_amdgcn_s_barrier();
  __builtin_amdgcn_sched_barrier(0);
}

// explicit-scalar load/store macros: no arrays, no pointer params -> no scratch.
#define LOADSET(A0,A1,B0,B1,F0,F1,F2,F3,itv) { int k0v = (itv) << 6;          \
  A0 = *(const int4*)(Az + (size_t)(bm + r)*lda + k0v + gc*8);                \
  A1 = *(const int4*)(Az + (size_t)(bm + 32 + r)*lda + k0v + gc*8);           \
  if constexpr (!CONVB) {                                                     \
    B0 = *(const int4*)(Bz16 + (size_t)(bnb + r)*ldb + k0v + gc*8);           \
    if constexpr (NB > 1)                                                     \
      B1 = *(const int4*)(Bz16 + (size_t)(bnb + 32 + r)*ldb + k0v + gc*8);    \
  } else {                                                                    \
    F0 = *(const float4*)(Bz32 + (size_t)(bnb + r)*ldb + k0v + gc*8);         \
    F1 = *(const float4*)(Bz32 + (size_t)(bnb + r)*ldb + k0v + gc*8 + 4);     \
    if constexpr (NB > 1) {                                                   \
      F2 = *(const float4*)(Bz32 + (size_t)(bnb + 32 + r)*ldb + k0v + gc*8);  \
      F3 = *(const float4*)(Bz32 + (size_t)(bnb + 32 + r)*ldb + k0v + gc*8 + 4); } } }

#define STORESET2(basep,A0,A1,B0,B1,F0,F1,F2,F3) {                            \
  char* bse = (basep);                                                        \
  *(int4*)(bse + r*128 + sl*16) = A0;                                         \
  *(int4*)(bse + (32 + r)*128 + sl*16) = A1;                                  \
  if constexpr (!CONVB) {                                                     \
    *(int4*)(bse + ABYTES + r*128 + sl*16) = B0;                              \
    if constexpr (NB > 1)                                                     \
      *(int4*)(bse + ABYTES + (32 + r)*128 + sl*16) = B1;                     \
  } else {                                                                    \
    *(int4*)(bse + ABYTES + r*128 + sl*16) = cvt8(F0, F1);                    \
    if constexpr (NB > 1)                                                     \
      *(int4*)(bse + ABYTES + (32 + r)*128 + sl*16) = cvt8(F2, F3); } }

// ---------------- kprep: fill Kh rows 512..575 (embk + l-tables, bf16) ------
__global__ __launch_bounds__(256) void kprep_kernel(
    const float* __restrict__ embk,
    const float* __restrict__ lqc, const float* __restrict__ lqt,
    const float* __restrict__ lcq, const float* __restrict__ ltq,
    unsigned short* __restrict__ Kh)
{
  int g = blockIdx.x*256 + threadIdx.x;       // 8 heads * 64 rows * 128
  if (g >= 8*64*128) return;
  int d = g & 127, rr = (g >> 7) & 63, h = g >> 13;
  float v = 0.f;
  if (rr < 50) v = embk[rr*128 + d];
  else if (rr < 62) {
    int u = rr - 50; int tb = u/3, f = u - tb*3;
    const float* tab = (tb==0) ? lqc : (tb==1) ? lqt : (tb==2) ? lcq : ltq;
    v = tab[f*128 + d];
  }
  Kh[((size_t)h*KLD + 512 + rr)*DKK + d] = f2bu(v);
}

// ---------------- LayerNorm: fp32 in, bf16 out ----------------
__global__ __launch_bounds__(256) void ln_bf16_kernel(const float* __restrict__ x,
    const float* __restrict__ g, const float* __restrict__ b,
    unsigned short* __restrict__ y)
{
  int row = blockIdx.x, t = threadIdx.x;
  const float4 xv = ((const float4*)(x + row*DD))[t];
  float s  = xv.x+xv.y+xv.z+xv.w;
  float ss = xv.x*xv.x+xv.y*xv.y+xv.z*xv.z+xv.w*xv.w;
  __shared__ float rs[256], rss[256];
  rs[t]=s; rss[t]=ss; __syncthreads();
  for (int st=128; st>0; st>>=1){ if (t<st){ rs[t]+=rs[t+st]; rss[t]+=rss[t+st]; } __syncthreads(); }
  float mean = rs[0] * (1.0f/DD);
  float var  = rss[0]*(1.0f/DD) - mean*mean;
  float inv  = rsqrtf(var + 1e-5f);
  float4 gv = ((const float4*)g)[t], bv = ((const float4*)b)[t];
  ushort4 ov;
  ov.x = f2bu((xv.x-mean)*inv*gv.x + bv.x);
  ov.y = f2bu((xv.y-mean)*inv*gv.y + bv.y);
  ov.z = f2bu((xv.z-mean)*inv*gv.z + bv.z);
  ov.w = f2bu((xv.w-mean)*inv*gv.w + bv.w);
  ((ushort4*)(y + row*DD))[t] = ov;
}

// ---------------- LayerNorm + out += b2 (split-K init) ----------------
__global__ __launch_bounds__(256) void ln_bf16_addb_kernel(float* __restrict__ x,
    const float* __restrict__ g, const float* __restrict__ b,
    const float* __restrict__ b2, unsigned short* __restrict__ y)
{
  int row = blockIdx.x, t = threadIdx.x;
  const float4 xv = ((const float4*)(x + row*DD))[t];
  float s  = xv.x+xv.y+xv.z+xv.w;
  float ss = xv.x*xv.x+xv.y*xv.y+xv.z*xv.z+xv.w*xv.w;
  __shared__ float rs[256], rss[256];
  rs[t]=s; rss[t]=ss; __syncthreads();
  for (int st=128; st>0; st>>=1){ if (t<st){ rs[t]+=rs[t+st]; rss[t]+=rss[t+st]; } __syncthreads(); }
  float mean = rs[0] * (1.0f/DD);
  float var  = rss[0]*(1.0f/DD) - mean*mean;
  float inv  = rsqrtf(var + 1e-5f);
  float4 gv = ((const float4*)g)[t], bv = ((const float4*)b)[t];
  ushort4 ov;
  ov.x = f2bu((xv.x-mean)*inv*gv.x + bv.x);
  ov.y = f2bu((xv.y-mean)*inv*gv.y + bv.y);
  ov.z = f2bu((xv.z-mean)*inv*gv.z + bv.z);
  ov.w = f2bu((xv.w-mean)*inv*gv.w + bv.w);
  ((ushort4*)(y + row*DD))[t] = ov;
  float4 b2v = ((const float4*)b2)[t];
  float4 nx; nx.x = xv.x+b2v.x; nx.y = xv.y+b2v.y; nx.z = xv.z+b2v.z; nx.w = xv.w+b2v.w;
  ((float4*)(x + row*DD))[t] = nx;
}

// ======== VGPR-staged pipelined bf16 MFMA GEMM; DEPTH = prefetch depth ======
template<int BN, int DEPTH, int CONVB, int ZK, int OUT_BF16, int RELU, int HAS_SRC, int HAS_BIAS>
__global__ __launch_bounds__(256) void gemm_pl(
    const unsigned short* __restrict__ A, int lda, size_t sAz,
    const void* __restrict__ Bv, int ldb, size_t sBz,
    const float* __restrict__ bias,
    const float* __restrict__ src, int ldsrc, size_t sSz,
    void* __restrict__ Cv, int ldc, size_t sCz,
    int K)
{
  constexpr int BM = 64;
  constexpr int WM = 32, WN = BN/2, FM = 2, FN = WN/16;
  constexpr int NB = BN/32;
  constexpr int ABYTES = BM*128, TILE = ABYTES + BN*128;
  __shared__ char lds[2*TILE];
  int t = threadIdx.x, w = t >> 6, l = t & 63;
  size_t z = blockIdx.z;
  const unsigned short* Az = A + z*sAz;
  const unsigned short* Bz16 = (const unsigned short*)Bv + (CONVB ? 0 : z*sBz);
  const float*          Bz32 = (const float*)Bv + (CONVB ? z*sBz : 0);
  int bm = blockIdx.y*BM, bn = blockIdx.x*BN;
  int bnb = bn;
  int wm = (w>>1)*WM, wn = (w&1)*WN;

  float4v acc[FM][FN];
  #pragma unroll
  for (int m=0;m<FM;++m)
    #pragma unroll
    for (int n=0;n<FN;++n) acc[m][n] = (float4v){0.f,0.f,0.f,0.f};

  int r = t >> 3, sl = t & 7;
  int gc = sl ^ (r & 7);
  int quad = l >> 4, lrow = l & 15;
  const int nit = K >> 6;   // DEPTH==2: nit even; DEPTH==4: nit % 4 == 0

  int4 Aa0, Aa1, Ab0, Ab1;  float4 Af0, Af1, Af2, Af3;
  int4 Ba0, Ba1, Bb0, Bb1;  float4 Bf0, Bf1, Bf2, Bf3;
  int4 Ca0, Ca1, Cb0, Cb1;  float4 Cf0, Cf1, Cf2, Cf3;
  int4 Da0, Da1, Db0, Db1;  float4 Df0, Df1, Df2, Df3;

  auto compute = [&](const char* base) {
    const char* ab = base;
    const char* bb = base + ABYTES;
    #pragma unroll
    for (int step=0; step<2; ++step) {
      int c = step*4 + quad;
      short8 af[FM], bf[FN];
      #pragma unroll
      for (int m=0;m<FM;++m) {
        int Rw = wm + m*16 + lrow;
        af[m] = *(const short8*)(ab + Rw*128 + ((c ^ (Rw & 7))*16));
      }
      #pragma unroll
      for (int n=0;n<FN;++n) {
        int Rw = wn + n*16 + lrow;
        bf[n] = *(const short8*)(bb + Rw*128 + ((c ^ (Rw & 7))*16));
      }
      #pragma unroll
      for (int m=0;m<FM;++m)
        #pragma unroll
        for (int n=0;n<FN;++n)
          acc[m][n] = __builtin_amdgcn_mfma_f32_16x16x32_bf16(af[m], bf[n], acc[m][n], 0, 0, 0);
    }
  };

  if constexpr (DEPTH == 2) {
    LOADSET(Aa0,Aa1,Ab0,Ab1,Af0,Af1,Af2,Af3, 0);
    LOADSET(Ba0,Ba1,Bb0,Bb1,Bf0,Bf1,Bf2,Bf3, 1);
    for (int it = 0; it < nit; it += 2) {
      STORESET2(lds, Aa0,Aa1,Ab0,Ab1,Af0,Af1,Af2,Af3);
      if (it + 2 < nit) LOADSET(Aa0,Aa1,Ab0,Ab1,Af0,Af1,Af2,Af3, it+2);
      lds_barrier();
      compute(lds);
      STORESET2(lds + TILE, Ba0,Ba1,Bb0,Bb1,Bf0,Bf1,Bf2,Bf3);
      if (it + 3 < nit) LOADSET(Ba0,Ba1,Bb0,Bb1,Bf0,Bf1,Bf2,Bf3, it+3);
      lds_barrier();
      compute(lds + TILE);
    }
  } else {
    LOADSET(Aa0,Aa1,Ab0,Ab1,Af0,Af1,Af2,Af3, 0);
    LOADSET(Ba0,Ba1,Bb0,Bb1,Bf0,Bf1,Bf2,Bf3, 1);
    LOADSET(Ca0,Ca1,Cb0,Cb1,Cf0,Cf1,Cf2,Cf3, 2);
    LOADSET(Da0,Da1,Db0,Db1,Df0,Df1,Df2,Df3, 3);
    for (int it = 0; it < nit; it += 4) {
      STORESET2(lds, Aa0,Aa1,Ab0,Ab1,Af0,Af1,Af2,Af3);
      if (it + 4 < nit) LOADSET(Aa0,Aa1,Ab0,Ab1,Af0,Af1,Af2,Af3, it+4);
      lds_barrier();
      compute(lds);
      STORESET2(lds + TILE, Ba0,Ba1,Bb0,Bb1,Bf0,Bf1,Bf2,Bf3);
      if (it + 5 < nit) LOADSET(Ba0,Ba1,Bb0,Bb1,Bf0,Bf1,Bf2,Bf3, it+5);
      lds_barrier();
      compute(lds + TILE);
      STORESET2(lds, Ca0,Ca1,Cb0,Cb1,Cf0,Cf1,Cf2,Cf3);
      if (it + 6 < nit) LOADSET(Ca0,Ca1,Cb0,Cb1,Cf0,Cf1,Cf2,Cf3, it+6);
      lds_barrier();
      compute(lds);
      STORESET2(lds + TILE, Da0,Da1,Db0,Db1,Df0,Df1,Df2,Df3);
      if (it + 7 < nit) LOADSET(Da0,Da1,Db0,Db1,Df0,Df1,Df2,Df3, it+7);
      lds_barrier();
      compute(lds + TILE);
    }
  }

  #pragma unroll
  for (int m=0;m<FM;++m)
    #pragma unroll
    for (int n=0;n<FN;++n)
      #pragma unroll
      for (int rg=0;rg<4;++rg) {
        int row = bm + wm + m*16 + quad*4 + rg;
        int col = bn + wn + n*16 + lrow;
        float vv = acc[m][n][rg];
        if (ZK) {
          atomicAdd(&((float*)Cv)[(size_t)row*ldc + col], vv);
        } else {
          if (HAS_BIAS) vv += bias[col];
          if (HAS_SRC)  vv += src[z*sSz + (size_t)row*ldsrc + col];
          if (RELU) vv = fmaxf(vv, 0.f);
          if (OUT_BF16) ((unsigned short*)Cv)[z*sCz + (size_t)row*ldc + col] = f2bu(vv);
          else          ((float*)Cv)[z*sCz + (size_t)row*ldc + col] = vv;
        }
      }
}

// ---------------- QKV GEMM: fp32 weights direct, DEPTH4, head-scatter -------
__global__ __launch_bounds__(256) void gemm_qkv_pl(
    const unsigned short* __restrict__ A,
    const float* __restrict__ Wq, const float* __restrict__ Wk,
    const float* __restrict__ Wv,
    const float* __restrict__ bq, const float* __restrict__ bk,
    const float* __restrict__ bv,
    unsigned short* __restrict__ Qh, unsigned short* __restrict__ Kh,
    unsigned short* __restrict__ Vt)
{
  constexpr int BN = 64, CONVB = 1;
  constexpr int WM = 32, WN = 32, FM = 2, FN = 2;
  constexpr int NB = 2;
  constexpr int ABYTES = 64*128, TILE = ABYTES + BN*128;
  __shared__ char lds[2*TILE];
  int t = threadIdx.x, w = t >> 6, l = t & 63;
  int bm = blockIdx.y*64, bn = blockIdx.x*BN;
  int wm = (w>>1)*WM, wn = (w&1)*WN;
  const int lda = DD, ldb = DD, nit = DD >> 6;   // 16
  const unsigned short* Az = A;
  int part0 = bn >> 10;
  const float* Bz32 = (part0==0 ? Wq : part0==1 ? Wk : Wv) + (size_t)(bn & 1023)*DD;
  const unsigned short* Bz16 = nullptr; (void)Bz16;
  int bnb = 0;

  float4v acc[FM][FN];
  #pragma unroll
  for (int m=0;m<FM;++m)
    #pragma unroll
    for (int n=0;n<FN;++n) acc[m][n] = (float4v){0.f,0.f,0.f,0.f};

  int r = t >> 3, sl = t & 7;
  int gc = sl ^ (r & 7);
  int quad = l >> 4, lrow = l & 15;

  int4 Aa0, Aa1, Ab0, Ab1;  float4 Af0, Af1, Af2, Af3;
  int4 Ba0, Ba1, Bb0, Bb1;  float4 Bf0, Bf1, Bf2, Bf3;
  int4 Ca0, Ca1, Cb0, Cb1;  float4 Cf0, Cf1, Cf2, Cf3;
  int4 Da0, Da1, Db0, Db1;  float4 Df0, Df1, Df2, Df3;

  auto compute = [&](const char* base) {
    const char* ab = base;
    const char* bb = base + ABYTES;
    #pragma unroll
    for (int step=0; step<2; ++step) {
      int c = step*4 + quad;
      short8 af[FM], bf[FN];
      #pragma unroll
      for (int m=0;m<FM;++m) {
        int Rw = wm + m*16 + lrow;
        af[m] = *(const short8*)(ab + Rw*128 + ((c ^ (Rw & 7))*16));
      }
      #pragma unroll
      for (int n=0;n<FN;++n) {
        int Rw = wn + n*16 + lrow;
        bf[n] = *(const short8*)(bb + Rw*128 + ((c ^ (Rw & 7))*16));
      }
      #pragma unroll
      for (int m=0;m<FM;++m)
        #pragma unroll
        for (int n=0;n<FN;++n)
          acc[m][n] = __builtin_amdgcn_mfma_f32_16x16x32_bf16(af[m], bf[n], acc[m][n], 0, 0, 0);
    }
  };

  LOADSET(Aa0,Aa1,Ab0,Ab1,Af0,Af1,Af2,Af3, 0);
  LOADSET(Ba0,Ba1,Bb0,Bb1,Bf0,Bf1,Bf2,Bf3, 1);
  LOADSET(Ca0,Ca1,Cb0,Cb1,Cf0,Cf1,Cf2,Cf3, 2);
  LOADSET(Da0,Da1,Db0,Db1,Df0,Df1,Df2,Df3, 3);
  for (int it = 0; it < nit; it += 4) {
    STORESET2(lds, Aa0,Aa1,Ab0,Ab1,Af0,Af1,Af2,Af3);
    if (it + 4 < nit) LOADSET(Aa0,Aa1,Ab0,Ab1,Af0,Af1,Af2,Af3, it+4);
    lds_barrier();
    compute(lds);
    STORESET2(lds + TILE, Ba0,Ba1,Bb0,Bb1,Bf0,Bf1,Bf2,Bf3);
    if (it + 5 < nit) LOADSET(Ba0,Ba1,Bb0,Bb1,Bf0,Bf1,Bf2,Bf3, it+5);
    lds_barrier();
    compute(lds + TILE);
    STORESET2(lds, Ca0,Ca1,Cb0,Cb1,Cf0,Cf1,Cf2,Cf3);
    if (it + 6 < nit) LOADSET(Ca0,Ca1,Cb0,Cb1,Cf0,Cf1,Cf2,Cf3, it+6);
    lds_barrier();
    compute(lds);
    STORESET2(lds + TILE, Da0,Da1,Db0,Db1,Df0,Df1,Df2,Df3);
    if (it + 7 < nit) LOADSET(Da0,Da1,Db0,Db1,Df0,Df1,Df2,Df3, it+7);
    lds_barrier();
    compute(lds + TILE);
  }

  #pragma unroll
  for (int m=0;m<FM;++m)
    #pragma unroll
    for (int n=0;n<FN;++n)
      #pragma unroll
      for (int rg=0;rg<4;++rg) {
        int row = bm + wm + m*16 + quad*4 + rg;
        int col = bn + wn + n*16 + lrow;
        int part = col >> 10, hh = (col >> 7) & 7, d = col & 127;
        const float* bp = (part==0) ? bq : (part==1) ? bk : bv;
        float vv = acc[m][n][rg] + bp[col & 1023];
        unsigned short o = f2bu(vv);
        if (part == 0)      Qh[((size_t)hh*LL + row)*DKK + d] = o;
        else if (part == 1) Kh[((size_t)hh*KLD + row)*DKK + d] = o;
        else                Vt[((size_t)hh*DKK + d)*LL + row] = o;
      }
}

// ======== fused attention v2: 8 q-rows/block, grid 64x8, 2 blocks/CU ========
// single-pass unnormalized softmax; K/V double-buffered in LDS (1 barrier/tile);
// depth-2 VGPR prefetch.
// LDS map (bytes):
//   [0    , 2176 )  Qt   [8][136]  bf16 (stride 272)
//   [2176 , 19584)  KtA  [64][136] bf16 (stride 272)
//   [19584, 36992)  KtB  [64][136] bf16
//   [36992, 55744)  S    [8][586]  f32  (stride 2344 B; 586%32==10 -> 2-way max)
//   [55744, 57408)  pws  [8][52]   f32
//   [57408, 57536)  pf1  [8][4]    f32
//   [57536, 57664)  pf2  [8][4]    f32
//   [57664, 57696)  sinv [8]       f32
// phase-2/3 overlays (regions dead by then):
//   P  [8][520] bf16 stride 1040 @ 2176   (over KtA head; KtA dead after ph1)
//   VA [128][68] bf16 stride 136 @ 10496  (over KtA tail + KtB head)
//   VB [128][68] bf16 stride 136 @ 27904  (over KtB tail + S head; S dead after ph2)
#define A2_QROWB 272
#define A2_KROWB 272
#define A2_SROWD 586
#define A2_PROWB 1040
#define A2_VROWB 136
#define A2_OFF_KA 2176
#define A2_OFF_KB 19584
#define A2_OFF_S  36992
#define A2_OFF_P  2176
#define A2_OFF_VA 10496
#define A2_OFF_VB 27904
#define A2_OFF_PW 55744
#define A2_OFF_PF1 57408
#define A2_OFF_PF2 57536
#define A2_OFF_SI 57664
#define A2_LDS 57696

__global__ __launch_bounds__(256) void attn_fused(
    const unsigned short* __restrict__ Qh, const unsigned short* __restrict__ Kh,
    const unsigned short* __restrict__ Vt,
    const float* __restrict__ qcr, const float* __restrict__ cqr,
    const float* __restrict__ qtr, const float* __restrict__ tqr,
    const int* __restrict__ ct, const int* __restrict__ pred,
    const int* __restrict__ mask,
    const float* __restrict__ embv, const float* __restrict__ lqc_v,
    const float* __restrict__ lcq_v, const float* __restrict__ lqt_v,
    const float* __restrict__ ltq_v,
    unsigned short* __restrict__ obuf)
{
  __shared__ __align__(16) char lds[A2_LDS];
  const int t = threadIdx.x;
  const int w = t >> 6, l = t & 63, quad = l >> 4, lrow = l & 15;
  const int i0 = blockIdx.x * 8, h = blockIdx.y;

  // zero pws/pf/sinv region (488 floats)
  for (int k2 = t; k2 < 488; k2 += 256) ((float*)(lds + A2_OFF_PW))[k2] = 0.f;

  // stage Q tile [8][128]
  if (t < 128) {
    int qr = t >> 4, qc = t & 15;
    *(int4*)(lds + qr*A2_QROWB + qc*16) =
        *(const int4*)(Qh + ((size_t)h*LL + i0 + qr)*DKK + qc*8);
  }

  const int kr = t >> 4, kc = t & 15;   // K staging: 4 rows/thread
  int4 ka0,ka1,ka2,ka3, kb0,kb1,kb2,kb3;

#define A2_LOADKA(jtv) { size_t kb_ = (size_t)h*KLD + (size_t)(jtv)*64 + kr;   \
    ka0 = *(const int4*)(Kh + (kb_     )*DKK + kc*8);                          \
    ka1 = *(const int4*)(Kh + (kb_ + 16)*DKK + kc*8);                          \
    ka2 = *(const int4*)(Kh + (kb_ + 32)*DKK + kc*8);                          \
    ka3 = *(const int4*)(Kh + (kb_ + 48)*DKK + kc*8); }
#define A2_LOADKB(jtv) { size_t kb_ = (size_t)h*KLD + (size_t)(jtv)*64 + kr;   \
    kb0 = *(const int4*)(Kh + (kb_     )*DKK + kc*8);                          \
    kb1 = *(const int4*)(Kh + (kb_ + 16)*DKK + kc*8);                          \
    kb2 = *(const int4*)(Kh + (kb_ + 32)*DKK + kc*8);                          \
    kb3 = *(const int4*)(Kh + (kb_ + 48)*DKK + kc*8); }
#define A2_STOREKA() { char* p_ = lds + A2_OFF_KA;                             \
    *(int4*)(p_ + (kr     )*A2_KROWB + kc*16) = ka0;                           \
    *(int4*)(p_ + (kr + 16)*A2_KROWB + kc*16) = ka1;                           \
    *(int4*)(p_ + (kr + 32)*A2_KROWB + kc*16) = ka2;                           \
    *(int4*)(p_ + (kr + 48)*A2_KROWB + kc*16) = ka3; }
#define A2_STOREKB() { char* p_ = lds + A2_OFF_KB;                             \
    *(int4*)(p_ + (kr     )*A2_KROWB + kc*16) = kb0;                           \
    *(int4*)(p_ + (kr + 16)*A2_KROWB + kc*16) = kb1;                           \
    *(int4*)(p_ + (kr + 32)*A2_KROWB + kc*16) = kb2;                           \
    *(int4*)(p_ + (kr + 48)*A2_KROWB + kc*16) = kb3; }

  auto qk_tile = [&](const char* kb, int jt) {
    float4v acc = (float4v){0.f,0.f,0.f,0.f};
    #pragma unroll
    for (int kk = 0; kk < 4; ++kk) {
      int c = kk*4 + quad;
      short8 af = *(const short8*)(lds + lrow*A2_QROWB + c*16);
      short8 bf = *(const short8*)(kb + (w*16 + lrow)*A2_KROWB + c*16);
      acc = __builtin_amdgcn_mfma_f32_16x16x32_bf16(af, bf, acc, 0, 0, 0);
    }
    if (quad < 2) {
      #pragma unroll
      for (int rg = 0; rg < 4; ++rg)
        ((float*)(lds + A2_OFF_S))[(quad*4 + rg)*A2_SROWD + jt*64 + w*16 + lrow] = acc[rg];
    }
  };

  // ---- phase 1: S[8][576] = Q @ Kh^T; dbuf KtA/KtB, 1 barrier/tile ----
  A2_LOADKA(0); A2_LOADKB(1);
  A2_STOREKA(); A2_LOADKA(2); lds_barrier(); qk_tile(lds + A2_OFF_KA, 0);
  A2_STOREKB(); A2_LOADKB(3); lds_barrier(); qk_tile(lds + A2_OFF_KB, 1);
  A2_STOREKA(); A2_LOADKA(4); lds_barrier(); qk_tile(lds + A2_OFF_KA, 2);
  A2_STOREKB(); A2_LOADKB(5); lds_barrier(); qk_tile(lds + A2_OFF_KB, 3);
  A2_STOREKA(); A2_LOADKA(6); lds_barrier(); qk_tile(lds + A2_OFF_KA, 4);
  A2_STOREKB(); A2_LOADKB(7); lds_barrier(); qk_tile(lds + A2_OFF_KB, 5);
  A2_STOREKA(); A2_LOADKA(8); lds_barrier(); qk_tile(lds + A2_OFF_KA, 6);
  A2_STOREKB();               lds_barrier(); qk_tile(lds + A2_OFF_KB, 7);
  A2_STOREKA();               lds_barrier(); qk_tile(lds + A2_OFF_KA, 8);
  lds_barrier();

  // ---- phase 2: single-pass unnormalized softmax (32 lanes per row) ----
  const int row = t >> 5, l32 = t & 31;
  const int i = i0 + row;
  const float* Sp = (const float*)(lds + A2_OFF_S) + row*A2_SROWD;
  const int bse = (i0 < QQ) ? 562 : (i0 < QQ + CCC) ? 568 : 571;
  const float lq1a = Sp[bse], lq1b = Sp[bse+1], lq1c = Sp[bse+2];
  const float lq2a = Sp[565], lq2b = Sp[566], lq2c = Sp[567];

  const int vr = t >> 3, vc = t & 7;    // V staging: 4 d-rows/thread
  int4 va0,va1,va2,va3, vb0,vb1,vb2,vb3;
#define A2_LOADVA(itv) { size_t vb_ = (size_t)h*DKK + vr;                      \
    size_t vo_ = (size_t)(itv)*64 + vc*8;                                      \
    va0 = *(const int4*)(Vt + (vb_      )*LL + vo_);                           \
    va1 = *(const int4*)(Vt + (vb_ + 32)*LL + vo_);                            \
    va2 = *(const int4*)(Vt + (vb_ + 64)*LL + vo_);                            \
    va3 = *(const int4*)(Vt + (vb_ + 96)*LL + vo_); }
#define A2_LOADVB(itv) { size_t vb_ = (size_t)h*DKK + vr;                      \
    size_t vo_ = (size_t)(itv)*64 + vc*8;                                      \
    vb0 = *(const int4*)(Vt + (vb_      )*LL + vo_);                           \
    vb1 = *(const int4*)(Vt + (vb_ + 32)*LL + vo_);                            \
    vb2 = *(const int4*)(Vt + (vb_ + 64)*LL + vo_);                            \
    vb3 = *(const int4*)(Vt + (vb_ + 96)*LL + vo_); }
#define A2_STOREVA() { char* p_ = lds + A2_OFF_VA;                             \
    *(int4*)(p_ + (vr     )*A2_VROWB + vc*16) = va0;                           \
    *(int4*)(p_ + (vr + 32)*A2_VROWB + vc*16) = va1;                           \
    *(int4*)(p_ + (vr + 64)*A2_VROWB + vc*16) = va2;                           \
    *(int4*)(p_ + (vr + 96)*A2_VROWB + vc*16) = va3; }
#define A2_STOREVB() { char* p_ = lds + A2_OFF_VB;                             \
    *(int4*)(p_ + (vr     )*A2_VROWB + vc*16) = vb0;                           \
    *(int4*)(p_ + (vr + 32)*A2_VROWB + vc*16) = vb1;                           \
    *(int4*)(p_ + (vr + 64)*A2_VROWB + vc*16) = vb2;                           \
    *(int4*)(p_ + (vr + 96)*A2_VROWB + vc*16) = vb3; }

  A2_LOADVA(0); A2_LOADVB(1);           // prefetch V tiles 0,1 under softmax

  float sum=0.f, f0=0.f, f1=0.f, f2=0.f, g0=0.f, g1=0.f, g2=0.f;
  float* pwsrow = (float*)(lds + A2_OFF_PW) + row*52;
  #pragma unroll
  for (int m = 0; m < 16; ++m) {
    int j = m*32 + l32;
    int predv = pred[i*LL + j];
    int maskv = mask[i*LL + j];
    float s = Sp[j] + Sp[512 + predv];
    float c0=0.f, c1=0.f, c2=0.f; int rt; int scat2 = 0;
    if (i0 < QQ) {
      if (j < QQ) { s += Sp[512]; rt = 0; }
      else if (j < QQ + CCC) {
        const float* r3 = qcr + ((size_t)i*CCC + (j - QQ))*3;
        c0 = r3[0]; c1 = r3[1]; c2 = r3[2];
        s += c0*lq1a + c1*lq1b + c2*lq1c; rt = 1;
      } else {
        const float* r3 = qtr + ((size_t)i*TTT + (j - QQ - CCC))*3;
        c0 = r3[0]; c1 = r3[1]; c2 = r3[2];
        s += c0*lq2a + c1*lq2b + c2*lq2c; rt = 2;
      }
    } else {
      if (j < QQ) {
        const float* r3 = (i < QQ + CCC) ? cqr + ((size_t)(i - QQ)*QQ + j)*3
                                         : tqr + ((size_t)(i - QQ - CCC)*QQ + j)*3;
        c0 = r3[0]; c1 = r3[1]; c2 = r3[2];
        s += c0*lq1a + c1*lq1b + c2*lq1c; rt = 1;
      } else {
        scat2 = ct[(i - QQ)*(CCC + TTT) + (j - QQ)];
        s += Sp[512 + scat2]; rt = 0;
      }
    }
    s *= 0.08838834764831845f;
    float e = (maskv == 0) ? 0.f : __expf(s);
    sum += e;
    *(unsigned short*)(lds + A2_OFF_P + row*A2_PROWB + j*2) = f2bu(e);
    atomicAdd(pwsrow + predv, e);
    if (rt == 0)      atomicAdd(pwsrow + scat2, e);
    else if (rt == 1) { f0 += e*c0; f1 += e*c1; f2 += e*c2; }
    else              { g0 += e*c0; g1 += e*c1; g2 += e*c2; }
  }
  #pragma unroll
  for (int off = 16; off >= 1; off >>= 1) {
    sum += __shfl_xor(sum, off);
    f0 += __shfl_xor(f0, off); f1 += __shfl_xor(f1, off); f2 += __shfl_xor(f2, off);
    g0 += __shfl_xor(g0, off); g1 += __shfl_xor(g1, off); g2 += __shfl_xor(g2, off);
  }
  if (l32 == 0) {
    float* pf1 = (float*)(lds + A2_OFF_PF1) + row*4;
    float* pf2 = (float*)(lds + A2_OFF_PF2) + row*4;
    pf1[0] = f0; pf1[1] = f1; pf1[2] = f2;
    pf2[0] = g0; pf2[1] = g1; pf2[2] = g2;
    ((float*)(lds + A2_OFF_SI))[row] = 1.0f / sum;
  }

  // ---- phase 3: O[8][128] = E @ V^T; dbuf VA/VB, 1 barrier/tile ----
  float4v oacc0 = (float4v){0.f,0.f,0.f,0.f};
  float4v oacc1 = (float4v){0.f,0.f,0.f,0.f};
  auto pv_tile = [&](const char* vbase, int it) {
    #pragma unroll
    for (int kk = 0; kk < 2; ++kk) {
      int c = kk*4 + quad;
      short8 pa  = *(const short8*)(lds + A2_OFF_P + lrow*A2_PROWB + it*128 + c*16);
      short8 vf0 = *(const short8*)(vbase + (w*32 + lrow)*A2_VROWB + c*16);
      short8 vf1 = *(const short8*)(vbase + (w*32 + 16 + lrow)*A2_VROWB + c*16);
      oacc0 = __builtin_amdgcn_mfma_f32_16x16x32_bf16(pa, vf0, oacc0, 0, 0, 0);
      oacc1 = __builtin_amdgcn_mfma_f32_16x16x32_bf16(pa, vf1, oacc1, 0, 0, 0);
    }
  };
  A2_STOREVA(); A2_LOADVA(2); lds_barrier(); pv_tile(lds + A2_OFF_VA, 0);
  A2_STOREVB(); A2_LOADVB(3); lds_barrier(); pv_tile(lds + A2_OFF_VB, 1);
  A2_STOREVA(); A2_LOADVA(4); lds_barrier(); pv_tile(lds + A2_OFF_VA, 2);
  A2_STOREVB(); A2_LOADVB(5); lds_barrier(); pv_tile(lds + A2_OFF_VB, 3);
  A2_STOREVA(); A2_LOADVA(6); lds_barrier(); pv_tile(lds + A2_OFF_VA, 4);
  A2_STOREVB(); A2_LOADVB(7); lds_barrier(); pv_tile(lds + A2_OFF_VB, 5);
  A2_STOREVA();               lds_barrier(); pv_tile(lds + A2_OFF_VA, 6);
  A2_STOREVB();               lds_barrier(); pv_tile(lds + A2_OFF_VB, 7);

  // ---- epilogue: (oacc + pws@embv + pf@tables) * sinv -> obuf bf16 ----
  if (quad < 2) {
    const float* tab1 = (i0 < QQ) ? lqc_v : (i0 < QQ + CCC) ? lcq_v : ltq_v;
    const bool hasT2 = (i0 < QQ);
    const float* pws = (const float*)(lds + A2_OFF_PW);
    const float* sinv = (const float*)(lds + A2_OFF_SI);
    #pragma unroll
    for (int n = 0; n < 2; ++n) {
      int d = w*32 + n*16 + lrow;
      float a0=0.f, a1=0.f, a2=0.f, a3=0.f;
      #pragma unroll 5
      for (int rr = 0; rr < RR; ++rr) {
        float evv = embv[rr*DKK + d];
        a0 += pws[(quad*4+0)*52 + rr]*evv;
        a1 += pws[(quad*4+1)*52 + rr]*evv;
        a2 += pws[(quad*4+2)*52 + rr]*evv;
        a3 += pws[(quad*4+3)*52 + rr]*evv;
      }
      float t0 = tab1[d], t1 = tab1[DKK + d], t2 = tab1[2*DKK + d];
      float u0 = 0.f, u1 = 0.f, u2 = 0.f;
      if (hasT2) { u0 = lqt_v[d]; u1 = lqt_v[DKK + d]; u2 = lqt_v[2*DKK + d]; }
      #pragma unroll
      for (int rg = 0; rg < 4; ++rg) {
        int rw = quad*4 + rg;
        const float* pf1 = (const float*)(lds + A2_OFF_PF1) + rw*4;
        const float* pf2 = (const float*)(lds + A2_OFF_PF2) + rw*4;
        float aval = (rg==0) ? a0 : (rg==1) ? a1 : (rg==2) ? a2 : a3;
        float oval = (n==0) ? oacc0[rg] : oacc1[rg];
        float val = (oval + aval
                  + pf1[0]*t0 + pf1[1]*t1 + pf1[2]*t2
                  + pf2[0]*u0 + pf2[1]*u1 + pf2[2]*u2) * sinv[rw];
        obuf[(size_t)(i0 + rw)*DD + h*DKK + d] = f2bu(val);
      }
    }
  }
}

// ---------------- launch ----------------
extern "C" void kernel_launch(void* const* d_in, const int* in_sizes, int n_in,
                              void* d_out, int out_size, void* d_ws, size_t ws_size,
                              hipStream_t stream)
{
  const float* x    = (const float*)d_in[0];
  const float* qcr  = (const float*)d_in[1];
  const float* cqr  = (const float*)d_in[2];
  const float* qtr  = (const float*)d_in[3];
  const float* tqr  = (const float*)d_in[4];
  const int*   ct   = (const int*)d_in[5];
  const int*   pred = (const int*)d_in[6];
  const int*   mask = (const int*)d_in[7];
  const float* embk = (const float*)d_in[8];
  const float* embv = (const float*)d_in[9];
  const float* lqc_k = (const float*)d_in[10];
  const float* lqc_v = (const float*)d_in[11];
  const float* lcq_k = (const float*)d_in[12];
  const float* lcq_v = (const float*)d_in[13];
  const float* lqt_k = (const float*)d_in[14];
  const float* lqt_v = (const float*)d_in[15];
  const float* ltq_k = (const float*)d_in[16];
  const float* ltq_v = (const float*)d_in[17];
  const float* Wq = (const float*)d_in[18]; const float* bq = (const float*)d_in[19];
  const float* Wk = (const float*)d_in[20]; const float* bk = (const float*)d_in[21];
  const float* Wv = (const float*)d_in[22]; const float* bv = (const float*)d_in[23];
  const float* Wo = (const float*)d_in[24]; const float* bo = (const float*)d_in[25];
  const float* ln1_g = (const float*)d_in[26]; const float* ln1_b = (const float*)d_in[27];
  const float* ln2_g = (const float*)d_in[28]; const float* ln2_b = (const float*)d_in[29];
  const float* W1 = (const float*)d_in[30]; const float* b1 = (const float*)d_in[31];
  const float* W2 = (const float*)d_in[32]; const float* b2 = (const float*)d_in[33];
  float* out = (float*)d_out;

  float* wsf = (float*)d_ws;
  float* S    = wsf;                          // FFN hidden region (attention no longer uses it)
  float* o2   = S + (size_t)HH*LL*SLD;        // kept for layout stability (unused)
  unsigned short* ub = (unsigned short*)(o2 + (size_t)HH*LL*DKK);
  unsigned short* ybuf_b = ub;                        // [L,D]
  unsigned short* obuf_b = ybuf_b + LL*DD;            // [L,D]
  unsigned short* Qh     = obuf_b + LL*DD;            // [H][512][128]
  unsigned short* Kh     = Qh + (size_t)HH*LL*DKK;    // [H][576][128]
  unsigned short* Vt     = Kh + (size_t)HH*KLD*DKK;   // [H][128][512]
  unsigned short* hidden = (unsigned short*)S;        // [L][FFF] bf16

  // 1. fill Kh bias rows (independent of everything)
  kprep_kernel<<<(8*64*128 + 255)/256, 256, 0, stream>>>(
      embk, lqc_k, lqt_k, lcq_k, ltq_k, Kh);
  // 2. LN1 -> bf16
  ln_bf16_kernel<<<LL, 256, 0, stream>>>(x, ln1_g, ln1_b, ybuf_b);
  // 3. QKV GEMM (fp32 weights direct, depth-4) with head scatter
  gemm_qkv_pl<<<dim3(48, 8), 256, 0, stream>>>(ybuf_b, Wq, Wk, Wv, bq, bk, bv,
                                               Qh, Kh, Vt);
  // 4. fused attention v2: 8 rows/block, grid 64x8 (2 blocks/CU)
  attn_fused<<<dim3(64, 8), 256, 0, stream>>>(
      Qh, Kh, Vt, qcr, cqr, qtr, tqr, ct, pred, mask,
      embv, lqc_v, lcq_v, lqt_v, ltq_v, obuf_b);
  // 5. out-proj (fp32 Wo direct, depth-4) + residual(x) -> out
  gemm_pl<32,4,1,0,0,0,1,1><<<dim3(32, 8, 1), 256, 0, stream>>>(
      obuf_b, DD, 0, Wo, DD, 0, bo, x, DD, 0, out, DD, 0, DD);
  // 6. LN2 -> bf16, and out += b2 (split-K init)
  ln_bf16_addb_kernel<<<LL, 256, 0, stream>>>(out, ln2_g, ln2_b, b2, ybuf_b);
  // 7. FFN1 relu (fp32 W1 direct, depth-4) -> hidden bf16
  gemm_pl<64,4,1,0,1,1,0,1><<<dim3(64, 8, 1), 256, 0, stream>>>(
      ybuf_b, DD, 0, W1, DD, 0, b1, nullptr, 0, 0, hidden, FFF, 0, DD);
  // 8. FFN2 split-K x4 (fp32 W2 direct, depth-4), atomicAdd -> out
  gemm_pl<64,4,1,1,0,0,0,0><<<dim3(16, 8, 4), 256, 0, stream>>>(
      hidden, FFF, (size_t)1024, W2, FFF, (size_t)1024,
      nullptr, nullptr, 0, 0, out, DD, 0, 1024);
}

// Round 4
// 235.943 us; speedup vs baseline: 1.0672x; 1.0479x over previous
//
#include <hip/hip_runtime.h>
#include <hip/hip_bf16.h>

#define LL 512
#define DD 1024
#define HH 8
#define DKK 128
#define QQ 256
#define CCC 128
#define TTT 128
#define RR 50
#define FFF 4096
#define KLD 576          // Kh rows per head: 512 keys + 50 embk + 12 ltabs + 2 pad
#define SLD 576          // (kept for workspace layout arithmetic)

typedef __attribute__((ext_vector_type(8))) short short8;
typedef __attribute__((ext_vector_type(4))) float float4v;

__device__ __forceinline__ unsigned short f2bu(float f) {
  __hip_bfloat16 h = __float2bfloat16(f);
  unsigned short u; __builtin_memcpy(&u, &h, 2); return u;
}
__device__ __forceinline__ float b2f(unsigned short u) {
  unsigned int v = ((unsigned int)u) << 16;
  float f; __builtin_memcpy(&f, &v, 4); return f;
}
__device__ __forceinline__ int4 cvt8(float4 x, float4 y) {
  int4 o;
  o.x = (int)f2bu(x.x) | ((int)f2bu(x.y) << 16);
  o.y = (int)f2bu(x.z) | ((int)f2bu(x.w) << 16);
  o.z = (int)f2bu(y.x) | ((int)f2bu(y.y) << 16);
  o.w = (int)f2bu(y.z) | ((int)f2bu(y.w) << 16);
  return o;
}

// barrier draining only LDS (lgkmcnt(0)); global loads stay in flight.
__device__ __forceinline__ void lds_barrier() {
  __builtin_amdgcn_sched_barrier(0);
  __builtin_amdgcn_s_waitcnt(0xC07F);
  __builtin_amdgcn_s_barrier();
  __builtin_amdgcn_sched_barrier(0);
}

// explicit-scalar load/store macros: no arrays, no pointer params -> no scratch.
#define LOADSET(A0,A1,B0,B1,F0,F1,F2,F3,itv) { int k0v = (itv) << 6;          \
  A0 = *(const int4*)(Az + (size_t)(bm + r)*lda + k0v + gc*8);                \
  A1 = *(const int4*)(Az + (size_t)(bm + 32 + r)*lda + k0v + gc*8);           \
  if constexpr (!CONVB) {                                                     \
    B0 = *(const int4*)(Bz16 + (size_t)(bnb + r)*ldb + k0v + gc*8);           \
    if constexpr (NB > 1)                                                     \
      B1 = *(const int4*)(Bz16 + (size_t)(bnb + 32 + r)*ldb + k0v + gc*8);    \
  } else {                                                                    \
    F0 = *(const float4*)(Bz32 + (size_t)(bnb + r)*ldb + k0v + gc*8);         \
    F1 = *(const float4*)(Bz32 + (size_t)(bnb + r)*ldb + k0v + gc*8 + 4);     \
    if constexpr (NB > 1) {                                                   \
      F2 = *(const float4*)(Bz32 + (size_t)(bnb + 32 + r)*ldb + k0v + gc*8);  \
      F3 = *(const float4*)(Bz32 + (size_t)(bnb + 32 + r)*ldb + k0v + gc*8 + 4); } } }

#define STORESET2(basep,A0,A1,B0,B1,F0,F1,F2,F3) {                            \
  char* bse = (basep);                                                        \
  *(int4*)(bse + r*128 + sl*16) = A0;                                         \
  *(int4*)(bse + (32 + r)*128 + sl*16) = A1;                                  \
  if constexpr (!CONVB) {                                                     \
    *(int4*)(bse + ABYTES + r*128 + sl*16) = B0;                              \
    if constexpr (NB > 1)                                                     \
      *(int4*)(bse + ABYTES + (32 + r)*128 + sl*16) = B1;                     \
  } else {                                                                    \
    *(int4*)(bse + ABYTES + r*128 + sl*16) = cvt8(F0, F1);                    \
    if constexpr (NB > 1)                                                     \
      *(int4*)(bse + ABYTES + (32 + r)*128 + sl*16) = cvt8(F2, F3); } }

// ---- K layout: slice-major [h][16 slices c][576 rows][8 elems] (bf16) ----
// ---- V layout: slice-major [h][64 slices c][128 d  ][8 elems] (bf16) ----
// (slice c of K = dims c*8..c*8+7; slice c of V = keys c*8..c*8+7)

// ---------------- kprep: fill Kh rows 512..575 (embk + l-tables, bf16) ------
__global__ __launch_bounds__(256) void kprep_kernel(
    const float* __restrict__ embk,
    const float* __restrict__ lqc, const float* __restrict__ lqt,
    const float* __restrict__ lcq, const float* __restrict__ ltq,
    unsigned short* __restrict__ Kh)
{
  int g = blockIdx.x*256 + threadIdx.x;       // 8 heads * 64 rows * 128
  if (g >= 8*64*128) return;
  int d = g & 127, rr = (g >> 7) & 63, h = g >> 13;
  float v = 0.f;
  if (rr < 50) v = embk[rr*128 + d];
  else if (rr < 62) {
    int u = rr - 50; int tb = u/3, f = u - tb*3;
    const float* tab = (tb==0) ? lqc : (tb==1) ? lqt : (tb==2) ? lcq : ltq;
    v = tab[f*128 + d];
  }
  Kh[(((size_t)h*16 + (d>>3))*KLD + 512 + rr)*8 + (d&7)] = f2bu(v);
}

// ---------------- LayerNorm: fp32 in, bf16 out ----------------
__global__ __launch_bounds__(256) void ln_bf16_kernel(const float* __restrict__ x,
    const float* __restrict__ g, const float* __restrict__ b,
    unsigned short* __restrict__ y)
{
  int row = blockIdx.x, t = threadIdx.x;
  const float4 xv = ((const float4*)(x + row*DD))[t];
  float s  = xv.x+xv.y+xv.z+xv.w;
  float ss = xv.x*xv.x+xv.y*xv.y+xv.z*xv.z+xv.w*xv.w;
  __shared__ float rs[256], rss[256];
  rs[t]=s; rss[t]=ss; __syncthreads();
  for (int st=128; st>0; st>>=1){ if (t<st){ rs[t]+=rs[t+st]; rss[t]+=rss[t+st]; } __syncthreads(); }
  float mean = rs[0] * (1.0f/DD);
  float var  = rss[0]*(1.0f/DD) - mean*mean;
  float inv  = rsqrtf(var + 1e-5f);
  float4 gv = ((const float4*)g)[t], bv = ((const float4*)b)[t];
  ushort4 ov;
  ov.x = f2bu((xv.x-mean)*inv*gv.x + bv.x);
  ov.y = f2bu((xv.y-mean)*inv*gv.y + bv.y);
  ov.z = f2bu((xv.z-mean)*inv*gv.z + bv.z);
  ov.w = f2bu((xv.w-mean)*inv*gv.w + bv.w);
  ((ushort4*)(y + row*DD))[t] = ov;
}

// ---------------- LayerNorm + out += b2 (split-K init) ----------------
__global__ __launch_bounds__(256) void ln_bf16_addb_kernel(float* __restrict__ x,
    const float* __restrict__ g, const float* __restrict__ b,
    const float* __restrict__ b2, unsigned short* __restrict__ y)
{
  int row = blockIdx.x, t = threadIdx.x;
  const float4 xv = ((const float4*)(x + row*DD))[t];
  float s  = xv.x+xv.y+xv.z+xv.w;
  float ss = xv.x*xv.x+xv.y*xv.y+xv.z*xv.z+xv.w*xv.w;
  __shared__ float rs[256], rss[256];
  rs[t]=s; rss[t]=ss; __syncthreads();
  for (int st=128; st>0; st>>=1){ if (t<st){ rs[t]+=rs[t+st]; rss[t]+=rss[t+st]; } __syncthreads(); }
  float mean = rs[0] * (1.0f/DD);
  float var  = rss[0]*(1.0f/DD) - mean*mean;
  float inv  = rsqrtf(var + 1e-5f);
  float4 gv = ((const float4*)g)[t], bv = ((const float4*)b)[t];
  ushort4 ov;
  ov.x = f2bu((xv.x-mean)*inv*gv.x + bv.x);
  ov.y = f2bu((xv.y-mean)*inv*gv.y + bv.y);
  ov.z = f2bu((xv.z-mean)*inv*gv.z + bv.z);
  ov.w = f2bu((xv.w-mean)*inv*gv.w + bv.w);
  ((ushort4*)(y + row*DD))[t] = ov;
  float4 b2v = ((const float4*)b2)[t];
  float4 nx; nx.x = xv.x+b2v.x; nx.y = xv.y+b2v.y; nx.z = xv.z+b2v.z; nx.w = xv.w+b2v.w;
  ((float4*)(x + row*DD))[t] = nx;
}

// ======== VGPR-staged pipelined bf16 MFMA GEMM; DEPTH = prefetch depth ======
template<int BN, int DEPTH, int CONVB, int ZK, int OUT_BF16, int RELU, int HAS_SRC, int HAS_BIAS>
__global__ __launch_bounds__(256) void gemm_pl(
    const unsigned short* __restrict__ A, int lda, size_t sAz,
    const void* __restrict__ Bv, int ldb, size_t sBz,
    const float* __restrict__ bias,
    const float* __restrict__ src, int ldsrc, size_t sSz,
    void* __restrict__ Cv, int ldc, size_t sCz,
    int K)
{
  constexpr int BM = 64;
  constexpr int WM = 32, WN = BN/2, FM = 2, FN = WN/16;
  constexpr int NB = BN/32;
  constexpr int ABYTES = BM*128, TILE = ABYTES + BN*128;
  __shared__ char lds[2*TILE];
  int t = threadIdx.x, w = t >> 6, l = t & 63;
  size_t z = blockIdx.z;
  const unsigned short* Az = A + z*sAz;
  const unsigned short* Bz16 = (const unsigned short*)Bv + (CONVB ? 0 : z*sBz);
  const float*          Bz32 = (const float*)Bv + (CONVB ? z*sBz : 0);
  int bm = blockIdx.y*BM, bn = blockIdx.x*BN;
  int bnb = bn;
  int wm = (w>>1)*WM, wn = (w&1)*WN;

  float4v acc[FM][FN];
  #pragma unroll
  for (int m=0;m<FM;++m)
    #pragma unroll
    for (int n=0;n<FN;++n) acc[m][n] = (float4v){0.f,0.f,0.f,0.f};

  int r = t >> 3, sl = t & 7;
  int gc = sl ^ (r & 7);
  int quad = l >> 4, lrow = l & 15;
  const int nit = K >> 6;   // DEPTH==2: nit even; DEPTH==4: nit % 4 == 0

  int4 Aa0, Aa1, Ab0, Ab1;  float4 Af0, Af1, Af2, Af3;
  int4 Ba0, Ba1, Bb0, Bb1;  float4 Bf0, Bf1, Bf2, Bf3;
  int4 Ca0, Ca1, Cb0, Cb1;  float4 Cf0, Cf1, Cf2, Cf3;
  int4 Da0, Da1, Db0, Db1;  float4 Df0, Df1, Df2, Df3;

  auto compute = [&](const char* base) {
    const char* ab = base;
    const char* bb = base + ABYTES;
    #pragma unroll
    for (int step=0; step<2; ++step) {
      int c = step*4 + quad;
      short8 af[FM], bf[FN];
      #pragma unroll
      for (int m=0;m<FM;++m) {
        int Rw = wm + m*16 + lrow;
        af[m] = *(const short8*)(ab + Rw*128 + ((c ^ (Rw & 7))*16));
      }
      #pragma unroll
      for (int n=0;n<FN;++n) {
        int Rw = wn + n*16 + lrow;
        bf[n] = *(const short8*)(bb + Rw*128 + ((c ^ (Rw & 7))*16));
      }
      #pragma unroll
      for (int m=0;m<FM;++m)
        #pragma unroll
        for (int n=0;n<FN;++n)
          acc[m][n] = __builtin_amdgcn_mfma_f32_16x16x32_bf16(af[m], bf[n], acc[m][n], 0, 0, 0);
    }
  };

  if constexpr (DEPTH == 2) {
    LOADSET(Aa0,Aa1,Ab0,Ab1,Af0,Af1,Af2,Af3, 0);
    LOADSET(Ba0,Ba1,Bb0,Bb1,Bf0,Bf1,Bf2,Bf3, 1);
    for (int it = 0; it < nit; it += 2) {
      STORESET2(lds, Aa0,Aa1,Ab0,Ab1,Af0,Af1,Af2,Af3);
      if (it + 2 < nit) LOADSET(Aa0,Aa1,Ab0,Ab1,Af0,Af1,Af2,Af3, it+2);
      lds_barrier();
      compute(lds);
      STORESET2(lds + TILE, Ba0,Ba1,Bb0,Bb1,Bf0,Bf1,Bf2,Bf3);
      if (it + 3 < nit) LOADSET(Ba0,Ba1,Bb0,Bb1,Bf0,Bf1,Bf2,Bf3, it+3);
      lds_barrier();
      compute(lds + TILE);
    }
  } else {
    LOADSET(Aa0,Aa1,Ab0,Ab1,Af0,Af1,Af2,Af3, 0);
    LOADSET(Ba0,Ba1,Bb0,Bb1,Bf0,Bf1,Bf2,Bf3, 1);
    LOADSET(Ca0,Ca1,Cb0,Cb1,Cf0,Cf1,Cf2,Cf3, 2);
    LOADSET(Da0,Da1,Db0,Db1,Df0,Df1,Df2,Df3, 3);
    for (int it = 0; it < nit; it += 4) {
      STORESET2(lds, Aa0,Aa1,Ab0,Ab1,Af0,Af1,Af2,Af3);
      if (it + 4 < nit) LOADSET(Aa0,Aa1,Ab0,Ab1,Af0,Af1,Af2,Af3, it+4);
      lds_barrier();
      compute(lds);
      STORESET2(lds + TILE, Ba0,Ba1,Bb0,Bb1,Bf0,Bf1,Bf2,Bf3);
      if (it + 5 < nit) LOADSET(Ba0,Ba1,Bb0,Bb1,Bf0,Bf1,Bf2,Bf3, it+5);
      lds_barrier();
      compute(lds + TILE);
      STORESET2(lds, Ca0,Ca1,Cb0,Cb1,Cf0,Cf1,Cf2,Cf3);
      if (it + 6 < nit) LOADSET(Ca0,Ca1,Cb0,Cb1,Cf0,Cf1,Cf2,Cf3, it+6);
      lds_barrier();
      compute(lds);
      STORESET2(lds + TILE, Da0,Da1,Db0,Db1,Df0,Df1,Df2,Df3);
      if (it + 7 < nit) LOADSET(Da0,Da1,Db0,Db1,Df0,Df1,Df2,Df3, it+7);
      lds_barrier();
      compute(lds + TILE);
    }
  }

  #pragma unroll
  for (int m=0;m<FM;++m)
    #pragma unroll
    for (int n=0;n<FN;++n)
      #pragma unroll
      for (int rg=0;rg<4;++rg) {
        int row = bm + wm + m*16 + quad*4 + rg;
        int col = bn + wn + n*16 + lrow;
        float vv = acc[m][n][rg];
        if (ZK) {
          atomicAdd(&((float*)Cv)[(size_t)row*ldc + col], vv);
        } else {
          if (HAS_BIAS) vv += bias[col];
          if (HAS_SRC)  vv += src[z*sSz + (size_t)row*ldsrc + col];
          if (RELU) vv = fmaxf(vv, 0.f);
          if (OUT_BF16) ((unsigned short*)Cv)[z*sCz + (size_t)row*ldc + col] = f2bu(vv);
          else          ((float*)Cv)[z*sCz + (size_t)row*ldc + col] = vv;
        }
      }
}

// ---------------- QKV GEMM: fp32 weights direct, DEPTH4, head-scatter -------
__global__ __launch_bounds__(256) void gemm_qkv_pl(
    const unsigned short* __restrict__ A,
    const float* __restrict__ Wq, const float* __restrict__ Wk,
    const float* __restrict__ Wv,
    const float* __restrict__ bq, const float* __restrict__ bk,
    const float* __restrict__ bv,
    unsigned short* __restrict__ Qh, unsigned short* __restrict__ Kh,
    unsigned short* __restrict__ Vt)
{
  constexpr int BN = 64, CONVB = 1;
  constexpr int WM = 32, WN = 32, FM = 2, FN = 2;
  constexpr int NB = 2;
  constexpr int ABYTES = 64*128, TILE = ABYTES + BN*128;
  __shared__ char lds[2*TILE];
  int t = threadIdx.x, w = t >> 6, l = t & 63;
  int bm = blockIdx.y*64, bn = blockIdx.x*BN;
  int wm = (w>>1)*WM, wn = (w&1)*WN;
  const int lda = DD, ldb = DD, nit = DD >> 6;   // 16
  const unsigned short* Az = A;
  int part0 = bn >> 10;
  const float* Bz32 = (part0==0 ? Wq : part0==1 ? Wk : Wv) + (size_t)(bn & 1023)*DD;
  const unsigned short* Bz16 = nullptr; (void)Bz16;
  int bnb = 0;

  float4v acc[FM][FN];
  #pragma unroll
  for (int m=0;m<FM;++m)
    #pragma unroll
    for (int n=0;n<FN;++n) acc[m][n] = (float4v){0.f,0.f,0.f,0.f};

  int r = t >> 3, sl = t & 7;
  int gc = sl ^ (r & 7);
  int quad = l >> 4, lrow = l & 15;

  int4 Aa0, Aa1, Ab0, Ab1;  float4 Af0, Af1, Af2, Af3;
  int4 Ba0, Ba1, Bb0, Bb1;  float4 Bf0, Bf1, Bf2, Bf3;
  int4 Ca0, Ca1, Cb0, Cb1;  float4 Cf0, Cf1, Cf2, Cf3;
  int4 Da0, Da1, Db0, Db1;  float4 Df0, Df1, Df2, Df3;

  auto compute = [&](const char* base) {
    const char* ab = base;
    const char* bb = base + ABYTES;
    #pragma unroll
    for (int step=0; step<2; ++step) {
      int c = step*4 + quad;
      short8 af[FM], bf[FN];
      #pragma unroll
      for (int m=0;m<FM;++m) {
        int Rw = wm + m*16 + lrow;
        af[m] = *(const short8*)(ab + Rw*128 + ((c ^ (Rw & 7))*16));
      }
      #pragma unroll
      for (int n=0;n<FN;++n) {
        int Rw = wn + n*16 + lrow;
        bf[n] = *(const short8*)(bb + Rw*128 + ((c ^ (Rw & 7))*16));
      }
      #pragma unroll
      for (int m=0;m<FM;++m)
        #pragma unroll
        for (int n=0;n<FN;++n)
          acc[m][n] = __builtin_amdgcn_mfma_f32_16x16x32_bf16(af[m], bf[n], acc[m][n], 0, 0, 0);
    }
  };

  LOADSET(Aa0,Aa1,Ab0,Ab1,Af0,Af1,Af2,Af3, 0);
  LOADSET(Ba0,Ba1,Bb0,Bb1,Bf0,Bf1,Bf2,Bf3, 1);
  LOADSET(Ca0,Ca1,Cb0,Cb1,Cf0,Cf1,Cf2,Cf3, 2);
  LOADSET(Da0,Da1,Db0,Db1,Df0,Df1,Df2,Df3, 3);
  for (int it = 0; it < nit; it += 4) {
    STORESET2(lds, Aa0,Aa1,Ab0,Ab1,Af0,Af1,Af2,Af3);
    if (it + 4 < nit) LOADSET(Aa0,Aa1,Ab0,Ab1,Af0,Af1,Af2,Af3, it+4);
    lds_barrier();
    compute(lds);
    STORESET2(lds + TILE, Ba0,Ba1,Bb0,Bb1,Bf0,Bf1,Bf2,Bf3);
    if (it + 5 < nit) LOADSET(Ba0,Ba1,Bb0,Bb1,Bf0,Bf1,Bf2,Bf3, it+5);
    lds_barrier();
    compute(lds + TILE);
    STORESET2(lds, Ca0,Ca1,Cb0,Cb1,Cf0,Cf1,Cf2,Cf3);
    if (it + 6 < nit) LOADSET(Ca0,Ca1,Cb0,Cb1,Cf0,Cf1,Cf2,Cf3, it+6);
    lds_barrier();
    compute(lds);
    STORESET2(lds + TILE, Da0,Da1,Db0,Db1,Df0,Df1,Df2,Df3);
    if (it + 7 < nit) LOADSET(Da0,Da1,Db0,Db1,Df0,Df1,Df2,Df3, it+7);
    lds_barrier();
    compute(lds + TILE);
  }

  #pragma unroll
  for (int m=0;m<FM;++m)
    #pragma unroll
    for (int n=0;n<FN;++n)
      #pragma unroll
      for (int rg=0;rg<4;++rg) {
        int row = bm + wm + m*16 + quad*4 + rg;
        int col = bn + wn + n*16 + lrow;
        int part = col >> 10, hh = (col >> 7) & 7, d = col & 127;
        const float* bp = (part==0) ? bq : (part==1) ? bk : bv;
        float vv = acc[m][n][rg] + bp[col & 1023];
        unsigned short o = f2bu(vv);
        if (part == 0)      Qh[((size_t)hh*LL + row)*DKK + d] = o;
        else if (part == 1) Kh[(((size_t)hh*16 + (d>>3))*KLD + row)*8 + (d&7)] = o;
        else                Vt[(((size_t)hh*64 + (row>>3))*128 + d)*8 + (row&7)] = o;
      }
}

// ======== fused attention v3: direct-global K/V MFMA operands, 4 barriers ====
// grid (64,8), 256 thr. K/V in slice-major layout -> B-fragments load coalesced
// straight from L2; no K/V LDS staging at all.
// LDS map (bytes):
//   [0    , 2176 )  Qt   [8][136]  bf16 (stride 272)
//   [2176 , 10496)  P    [8][520]  bf16 (stride 1040)
//   [10496, 29184)  S    [8][584]  f32  (stride 2336 B)
//   [29184, 30848)  pws  [8][52]   f32
//   [30848, 30976)  pf1  [8][4]    f32
//   [30976, 31104)  pf2  [8][4]    f32
//   [31104, 31136)  sinv [8]       f32
//   [31136, 35360)  o2s  [8][132]  f32
#define A3_QROWB 272
#define A3_PROWB 1040
#define A3_SROWD 584
#define A3_O2ROW 132
#define A3_OFF_P   2176
#define A3_OFF_S   10496
#define A3_OFF_PW  29184
#define A3_OFF_PF1 30848
#define A3_OFF_PF2 30976
#define A3_OFF_SI  31104
#define A3_OFF_O2  31136
#define A3_LDS     35360

__global__ __launch_bounds__(256) void attn_fused(
    const unsigned short* __restrict__ Qh, const unsigned short* __restrict__ Kh,
    const unsigned short* __restrict__ Vt,
    const float* __restrict__ qcr, const float* __restrict__ cqr,
    const float* __restrict__ qtr, const float* __restrict__ tqr,
    const int* __restrict__ ct, const int* __restrict__ pred,
    const int* __restrict__ mask,
    const float* __restrict__ embv, const float* __restrict__ lqc_v,
    const float* __restrict__ lcq_v, const float* __restrict__ lqt_v,
    const float* __restrict__ ltq_v,
    unsigned short* __restrict__ obuf)
{
  __shared__ __align__(16) char lds[A3_LDS];
  const int t = threadIdx.x;
  const int w = t >> 6, l = t & 63, quad = l >> 4, lrow = l & 15;
  const int i0 = blockIdx.x * 8, h = blockIdx.y;

  // zero pws/pf/sinv region (488 floats)
  for (int k2 = t; k2 < 488; k2 += 256) ((float*)(lds + A3_OFF_PW))[k2] = 0.f;

  // stage Q tile [8][128]
  if (t < 128) {
    int qr = t >> 4, qc = t & 15;
    *(int4*)(lds + qr*A3_QROWB + qc*16) =
        *(const int4*)(Qh + ((size_t)h*LL + i0 + qr)*DKK + qc*8);
  }
  lds_barrier();    // barrier 1: Qt + zeroed pws visible

  // ---- phase 1: S[8][576] = Q @ Kh^T, K fragments direct from global ----
  {
    const unsigned short* Kc = Kh + (size_t)h*16*KLD*8;
    short8 af0 = *(const short8*)(lds + lrow*A3_QROWB + (quad     )*16);
    short8 af1 = *(const short8*)(lds + lrow*A3_QROWB + (quad +  4)*16);
    short8 af2 = *(const short8*)(lds + lrow*A3_QROWB + (quad +  8)*16);
    short8 af3 = *(const short8*)(lds + lrow*A3_QROWB + (quad + 12)*16);
    #pragma unroll
    for (int jt = 0; jt < 9; ++jt) {
      float4v acc = (float4v){0.f,0.f,0.f,0.f};
      int krow = jt*64 + w*16 + lrow;
      short8 bf0 = *(const short8*)(Kc + ((size_t)(quad     )*KLD + krow)*8);
      short8 bf1 = *(const short8*)(Kc + ((size_t)(quad +  4)*KLD + krow)*8);
      short8 bf2 = *(const short8*)(Kc + ((size_t)(quad +  8)*KLD + krow)*8);
      short8 bf3 = *(const short8*)(Kc + ((size_t)(quad + 12)*KLD + krow)*8);
      acc = __builtin_amdgcn_mfma_f32_16x16x32_bf16(af0, bf0, acc, 0, 0, 0);
      acc = __builtin_amdgcn_mfma_f32_16x16x32_bf16(af1, bf1, acc, 0, 0, 0);
      acc = __builtin_amdgcn_mfma_f32_16x16x32_bf16(af2, bf2, acc, 0, 0, 0);
      acc = __builtin_amdgcn_mfma_f32_16x16x32_bf16(af3, bf3, acc, 0, 0, 0);
      if (quad < 2) {
        #pragma unroll
        for (int rg = 0; rg < 4; ++rg)
          ((float*)(lds + A3_OFF_S))[(quad*4 + rg)*A3_SROWD + jt*64 + w*16 + lrow] = acc[rg];
      }
    }
  }
  lds_barrier();    // barrier 2: S visible

  // ---- phase 2: single-pass unnormalized softmax (32 lanes per row) ----
  const int row = t >> 5, l32 = t & 31;
  const int i = i0 + row;
  const float* Sp = (const float*)(lds + A3_OFF_S) + row*A3_SROWD;
  const int bse = (i0 < QQ) ? 562 : (i0 < QQ + CCC) ? 568 : 571;
  const float lq1a = Sp[bse], lq1b = Sp[bse+1], lq1c = Sp[bse+2];
  const float lq2a = Sp[565], lq2b = Sp[566], lq2c = Sp[567];

  float sum=0.f, f0=0.f, f1=0.f, f2=0.f, g0=0.f, g1=0.f, g2=0.f;
  float* pwsrow = (float*)(lds + A3_OFF_PW) + row*52;
  #pragma unroll
  for (int m = 0; m < 16; ++m) {
    int j = m*32 + l32;
    int predv = pred[i*LL + j];
    int maskv = mask[i*LL + j];
    float s = Sp[j] + Sp[512 + predv];
    float c0=0.f, c1=0.f, c2=0.f; int rt; int scat2 = 0;
    if (i0 < QQ) {
      if (j < QQ) { s += Sp[512]; rt = 0; }
      else if (j < QQ + CCC) {
        const float* r3 = qcr + ((size_t)i*CCC + (j - QQ))*3;
        c0 = r3[0]; c1 = r3[1]; c2 = r3[2];
        s += c0*lq1a + c1*lq1b + c2*lq1c; rt = 1;
      } else {
        const float* r3 = qtr + ((size_t)i*TTT + (j - QQ - CCC))*3;
        c0 = r3[0]; c1 = r3[1]; c2 = r3[2];
        s += c0*lq2a + c1*lq2b + c2*lq2c; rt = 2;
      }
    } else {
      if (j < QQ) {
        const float* r3 = (i < QQ + CCC) ? cqr + ((size_t)(i - QQ)*QQ + j)*3
                                         : tqr + ((size_t)(i - QQ - CCC)*QQ + j)*3;
        c0 = r3[0]; c1 = r3[1]; c2 = r3[2];
        s += c0*lq1a + c1*lq1b + c2*lq1c; rt = 1;
      } else {
        scat2 = ct[(i - QQ)*(CCC + TTT) + (j - QQ)];
        s += Sp[512 + scat2]; rt = 0;
      }
    }
    s *= 0.08838834764831845f;
    float e = (maskv == 0) ? 0.f : __expf(s);
    sum += e;
    *(unsigned short*)(lds + A3_OFF_P + row*A3_PROWB + j*2) = f2bu(e);
    atomicAdd(pwsrow + predv, e);
    if (rt == 0)      atomicAdd(pwsrow + scat2, e);
    else if (rt == 1) { f0 += e*c0; f1 += e*c1; f2 += e*c2; }
    else              { g0 += e*c0; g1 += e*c1; g2 += e*c2; }
  }
  #pragma unroll
  for (int off = 16; off >= 1; off >>= 1) {
    sum += __shfl_xor(sum, off);
    f0 += __shfl_xor(f0, off); f1 += __shfl_xor(f1, off); f2 += __shfl_xor(f2, off);
    g0 += __shfl_xor(g0, off); g1 += __shfl_xor(g1, off); g2 += __shfl_xor(g2, off);
  }
  if (l32 == 0) {
    float* pf1 = (float*)(lds + A3_OFF_PF1) + row*4;
    float* pf2 = (float*)(lds + A3_OFF_PF2) + row*4;
    pf1[0] = f0; pf1[1] = f1; pf1[2] = f2;
    pf2[0] = g0; pf2[1] = g1; pf2[2] = g2;
    ((float*)(lds + A3_OFF_SI))[row] = 1.0f / sum;
  }
  lds_barrier();    // barrier 3: P/pws/pf/sinv visible; S reads done

  // ---- o2term: o2s[row][d] = pws@embv + pf@tables (f32), per-thread (row,d) ----
  {
    int orow = t >> 5, d0 = (t & 31)*4;
    const float* pwsr = (const float*)(lds + A3_OFF_PW) + orow*52;
    float a0=0.f, a1=0.f, a2=0.f, a3=0.f;
    #pragma unroll 5
    for (int rr = 0; rr < RR; ++rr) {
      float pv = pwsr[rr];
      float4 ev = *(const float4*)(embv + rr*DKK + d0);
      a0 += pv*ev.x; a1 += pv*ev.y; a2 += pv*ev.z; a3 += pv*ev.w;
    }
    const float* tab1 = (i0 < QQ) ? lqc_v : (i0 < QQ + CCC) ? lcq_v : ltq_v;
    const float* pf1 = (const float*)(lds + A3_OFF_PF1) + orow*4;
    float4 t0 = *(const float4*)(tab1 + d0);
    float4 t1 = *(const float4*)(tab1 + DKK + d0);
    float4 t2 = *(const float4*)(tab1 + 2*DKK + d0);
    a0 += pf1[0]*t0.x + pf1[1]*t1.x + pf1[2]*t2.x;
    a1 += pf1[0]*t0.y + pf1[1]*t1.y + pf1[2]*t2.y;
    a2 += pf1[0]*t0.z + pf1[1]*t1.z + pf1[2]*t2.z;
    a3 += pf1[0]*t0.w + pf1[1]*t1.w + pf1[2]*t2.w;
    if (i0 < QQ) {
      const float* pf2 = (const float*)(lds + A3_OFF_PF2) + orow*4;
      float4 u0 = *(const float4*)(lqt_v + d0);
      float4 u1 = *(const float4*)(lqt_v + DKK + d0);
      float4 u2 = *(const float4*)(lqt_v + 2*DKK + d0);
      a0 += pf2[0]*u0.x + pf2[1]*u1.x + pf2[2]*u2.x;
      a1 += pf2[0]*u0.y + pf2[1]*u1.y + pf2[2]*u2.y;
      a2 += pf2[0]*u0.z + pf2[1]*u1.z + pf2[2]*u2.z;
      a3 += pf2[0]*u0.w + pf2[1]*u1.w + pf2[2]*u2.w;
    }
    float4 av; av.x=a0; av.y=a1; av.z=a2; av.w=a3;
    *(float4*)((float*)(lds + A3_OFF_O2) + orow*A3_O2ROW + d0) = av;
  }
  lds_barrier();    // barrier 4: o2s visible

  // ---- phase 3: O[8][128] = E @ V^T, V fragments direct from global; no barriers ----
  float4v oacc0 = (float4v){0.f,0.f,0.f,0.f};
  float4v oacc1 = (float4v){0.f,0.f,0.f,0.f};
  {
    const unsigned short* Vc = Vt + (size_t)h*64*128*8;
    #pragma unroll
    for (int it = 0; it < 8; ++it) {
      #pragma unroll
      for (int kk = 0; kk < 2; ++kk) {
        int c = kk*4 + quad;
        short8 pa  = *(const short8*)(lds + A3_OFF_P + lrow*A3_PROWB + it*128 + c*16);
        short8 vf0 = *(const short8*)(Vc + (((size_t)(it*8 + c))*128 + w*32 + lrow)*8);
        short8 vf1 = *(const short8*)(Vc + (((size_t)(it*8 + c))*128 + w*32 + 16 + lrow)*8);
        oacc0 = __builtin_amdgcn_mfma_f32_16x16x32_bf16(pa, vf0, oacc0, 0, 0, 0);
        oacc1 = __builtin_amdgcn_mfma_f32_16x16x32_bf16(pa, vf1, oacc1, 0, 0, 0);
      }
    }
  }

  // ---- epilogue: (oacc + o2s) * sinv -> obuf bf16 ----
  if (quad < 2) {
    const float* o2s = (const float*)(lds + A3_OFF_O2);
    const float* sinv = (const float*)(lds + A3_OFF_SI);
    #pragma unroll
    for (int n = 0; n < 2; ++n) {
      int d = w*32 + n*16 + lrow;
      #pragma unroll
      for (int rg = 0; rg < 4; ++rg) {
        int rw = quad*4 + rg;
        float oval = (n==0) ? oacc0[rg] : oacc1[rg];
        float val = (oval + o2s[rw*A3_O2ROW + d]) * sinv[rw];
        obuf[(size_t)(i0 + rw)*DD + h*DKK + d] = f2bu(val);
      }
    }
  }
}

// ---------------- launch ----------------
extern "C" void kernel_launch(void* const* d_in, const int* in_sizes, int n_in,
                              void* d_out, int out_size, void* d_ws, size_t ws_size,
                              hipStream_t stream)
{
  const float* x    = (const float*)d_in[0];
  const float* qcr  = (const float*)d_in[1];
  const float* cqr  = (const float*)d_in[2];
  const float* qtr  = (const float*)d_in[3];
  const float* tqr  = (const float*)d_in[4];
  const int*   ct   = (const int*)d_in[5];
  const int*   pred = (const int*)d_in[6];
  const int*   mask = (const int*)d_in[7];
  const float* embk = (const float*)d_in[8];
  const float* embv = (const float*)d_in[9];
  const float* lqc_k = (const float*)d_in[10];
  const float* lqc_v = (const float*)d_in[11];
  const float* lcq_k = (const float*)d_in[12];
  const float* lcq_v = (const float*)d_in[13];
  const float* lqt_k = (const float*)d_in[14];
  const float* lqt_v = (const float*)d_in[15];
  const float* ltq_k = (const float*)d_in[16];
  const float* ltq_v = (const float*)d_in[17];
  const float* Wq = (const float*)d_in[18]; const float* bq = (const float*)d_in[19];
  const float* Wk = (const float*)d_in[20]; const float* bk = (const float*)d_in[21];
  const float* Wv = (const float*)d_in[22]; const float* bv = (const float*)d_in[23];
  const float* Wo = (const float*)d_in[24]; const float* bo = (const float*)d_in[25];
  const float* ln1_g = (const float*)d_in[26]; const float* ln1_b = (const float*)d_in[27];
  const float* ln2_g = (const float*)d_in[28]; const float* ln2_b = (const float*)d_in[29];
  const float* W1 = (const float*)d_in[30]; const float* b1 = (const float*)d_in[31];
  const float* W2 = (const float*)d_in[32]; const float* b2 = (const float*)d_in[33];
  float* out = (float*)d_out;

  float* wsf = (float*)d_ws;
  float* S    = wsf;                          // FFN hidden region (attention no longer uses it)
  float* o2   = S + (size_t)HH*LL*SLD;        // kept for layout stability (unused)
  unsigned short* ub = (unsigned short*)(o2 + (size_t)HH*LL*DKK);
  unsigned short* ybuf_b = ub;                        // [L,D]
  unsigned short* obuf_b = ybuf_b + LL*DD;            // [L,D]
  unsigned short* Qh     = obuf_b + LL*DD;            // [H][512][128]
  unsigned short* Kh     = Qh + (size_t)HH*LL*DKK;    // [H][16][576][8] slice-major
  unsigned short* Vt     = Kh + (size_t)HH*KLD*DKK;   // [H][64][128][8] slice-major
  unsigned short* hidden = (unsigned short*)S;        // [L][FFF] bf16

  // 1. fill Kh bias rows (independent of everything)
  kprep_kernel<<<(8*64*128 + 255)/256, 256, 0, stream>>>(
      embk, lqc_k, lqt_k, lcq_k, ltq_k, Kh);
  // 2. LN1 -> bf16
  ln_bf16_kernel<<<LL, 256, 0, stream>>>(x, ln1_g, ln1_b, ybuf_b);
  // 3. QKV GEMM (fp32 weights direct, depth-4) with head scatter
  gemm_qkv_pl<<<dim3(48, 8), 256, 0, stream>>>(ybuf_b, Wq, Wk, Wv, bq, bk, bv,
                                               Qh, Kh, Vt);
  // 4. fused attention v3: direct-global K/V, 4 barriers
  attn_fused<<<dim3(64, 8), 256, 0, stream>>>(
      Qh, Kh, Vt, qcr, cqr, qtr, tqr, ct, pred, mask,
      embv, lqc_v, lcq_v, lqt_v, ltq_v, obuf_b);
  // 5. out-proj (fp32 Wo direct, depth-4) + residual(x) -> out
  gemm_pl<32,4,1,0,0,0,1,1><<<dim3(32, 8, 1), 256, 0, stream>>>(
      obuf_b, DD, 0, Wo, DD, 0, bo, x, DD, 0, out, DD, 0, DD);
  // 6. LN2 -> bf16, and out += b2 (split-K init)
  ln_bf16_addb_kernel<<<LL, 256, 0, stream>>>(out, ln2_g, ln2_b, b2, ybuf_b);
  // 7. FFN1 relu (fp32 W1 direct, depth-4) -> hidden bf16
  gemm_pl<64,4,1,0,1,1,0,1><<<dim3(64, 8, 1), 256, 0, stream>>>(
      ybuf_b, DD, 0, W1, DD, 0, b1, nullptr, 0, 0, hidden, FFF, 0, DD);
  // 8. FFN2 split-K x4 (fp32 W2 direct, depth-4), atomicAdd -> out
  gemm_pl<64,4,1,1,0,0,0,0><<<dim3(16, 8, 4), 256, 0, stream>>>(
      hidden, FFF, (size_t)1024, W2, FFF, (size_t)1024,
      nullptr, nullptr, 0, 0, out, DD, 0, 1024);
}

// Round 5
// 230.410 us; speedup vs baseline: 1.0928x; 1.0240x over previous
//
#include <hip/hip_runtime.h>
#include <hip/hip_bf16.h>

#define LL 512
#define DD 1024
#define HH 8
#define DKK 128
#define QQ 256
#define CCC 128
#define TTT 128
#define RR 50
#define FFF 4096
#define KLD 576          // Kh rows per head: 512 keys + 50 embk + 12 ltabs + 2 pad
#define SLD 576          // (kept for workspace layout arithmetic)

typedef __attribute__((ext_vector_type(8))) short short8;
typedef __attribute__((ext_vector_type(4))) float float4v;

__device__ __forceinline__ unsigned short f2bu(float f) {
  __hip_bfloat16 h = __float2bfloat16(f);
  unsigned short u; __builtin_memcpy(&u, &h, 2); return u;
}
__device__ __forceinline__ float b2f(unsigned short u) {
  unsigned int v = ((unsigned int)u) << 16;
  float f; __builtin_memcpy(&f, &v, 4); return f;
}
__device__ __forceinline__ int4 cvt8(float4 x, float4 y) {
  int4 o;
  o.x = (int)f2bu(x.x) | ((int)f2bu(x.y) << 16);
  o.y = (int)f2bu(x.z) | ((int)f2bu(x.w) << 16);
  o.z = (int)f2bu(y.x) | ((int)f2bu(y.y) << 16);
  o.w = (int)f2bu(y.z) | ((int)f2bu(y.w) << 16);
  return o;
}

// barrier draining only LDS (lgkmcnt(0)); global loads stay in flight.
__device__ __forceinline__ void lds_barrier() {
  __builtin_amdgcn_sched_barrier(0);
  __builtin_amdgcn_s_waitcnt(0xC07F);
  __builtin_amdgcn_s_barrier();
  __builtin_amdgcn_sched_barrier(0);
}

// explicit-scalar load/store macros: no arrays, no pointer params -> no scratch.
#define LOADSET(A0,A1,B0,B1,F0,F1,F2,F3,itv) { int k0v = (itv) << 6;          \
  A0 = *(const int4*)(Az + (size_t)(bm + r)*lda + k0v + gc*8);                \
  A1 = *(const int4*)(Az + (size_t)(bm + 32 + r)*lda + k0v + gc*8);           \
  if constexpr (!CONVB) {                                                     \
    B0 = *(const int4*)(Bz16 + (size_t)(bnb + r)*ldb + k0v + gc*8);           \
    if constexpr (NB > 1)                                                     \
      B1 = *(const int4*)(Bz16 + (size_t)(bnb + 32 + r)*ldb + k0v + gc*8);    \
  } else {                                                                    \
    F0 = *(const float4*)(Bz32 + (size_t)(bnb + r)*ldb + k0v + gc*8);         \
    F1 = *(const float4*)(Bz32 + (size_t)(bnb + r)*ldb + k0v + gc*8 + 4);     \
    if constexpr (NB > 1) {                                                   \
      F2 = *(const float4*)(Bz32 + (size_t)(bnb + 32 + r)*ldb + k0v + gc*8);  \
      F3 = *(const float4*)(Bz32 + (size_t)(bnb + 32 + r)*ldb + k0v + gc*8 + 4); } } }

#define STORESET2(basep,A0,A1,B0,B1,F0,F1,F2,F3) {                            \
  char* bse = (basep);                                                        \
  *(int4*)(bse + r*128 + sl*16) = A0;                                         \
  *(int4*)(bse + (32 + r)*128 + sl*16) = A1;                                  \
  if constexpr (!CONVB) {                                                     \
    *(int4*)(bse + ABYTES + r*128 + sl*16) = B0;                              \
    if constexpr (NB > 1)                                                     \
      *(int4*)(bse + ABYTES + (32 + r)*128 + sl*16) = B1;                     \
  } else {                                                                    \
    *(int4*)(bse + ABYTES + r*128 + sl*16) = cvt8(F0, F1);                    \
    if constexpr (NB > 1)                                                     \
      *(int4*)(bse + ABYTES + (32 + r)*128 + sl*16) = cvt8(F2, F3); } }

// 8-wave (BM=128) variants: A = 2 int4/thread, B = 1 int4 (or 2 float4 cvt).
#define LOADSET8(A0,A1,B0,F0,F1,itv) { int k0v = (itv) << 6;                  \
  A0 = *(const int4*)(Az + (size_t)(bm + r)*lda + k0v + gc*8);                \
  A1 = *(const int4*)(Az + (size_t)(bm + 64 + r)*lda + k0v + gc*8);           \
  if constexpr (!CONVB) {                                                     \
    B0 = *(const int4*)(Bz16 + (size_t)(bnb + r)*ldb + k0v + gc*8);           \
  } else {                                                                    \
    F0 = *(const float4*)(Bz32 + (size_t)(bnb + r)*ldb + k0v + gc*8);         \
    F1 = *(const float4*)(Bz32 + (size_t)(bnb + r)*ldb + k0v + gc*8 + 4); } }

#define STORESET8(basep,A0,A1,B0,F0,F1) {                                     \
  char* bse = (basep);                                                        \
  *(int4*)(bse + r*128 + sl*16) = A0;                                         \
  *(int4*)(bse + (64 + r)*128 + sl*16) = A1;                                  \
  if constexpr (!CONVB) {                                                     \
    *(int4*)(bse + ABYTES + r*128 + sl*16) = B0;                              \
  } else {                                                                    \
    *(int4*)(bse + ABYTES + r*128 + sl*16) = cvt8(F0, F1); } }

// ---- K layout: slice-major [h][16 slices c][576 rows][8 elems] (bf16) ----
// ---- V layout: slice-major [h][64 slices c][128 d  ][8 elems] (bf16) ----

// ---------------- LayerNorm: fp32 in, bf16 out; + fused kprep ----------------
__global__ __launch_bounds__(256) void ln_bf16_kernel(const float* __restrict__ x,
    const float* __restrict__ g, const float* __restrict__ b,
    unsigned short* __restrict__ y,
    const float* __restrict__ embk,
    const float* __restrict__ lqc, const float* __restrict__ lqt,
    const float* __restrict__ lcq, const float* __restrict__ ltq,
    unsigned short* __restrict__ Kh)
{
  int row = blockIdx.x, t = threadIdx.x;
  const float4 xv = ((const float4*)(x + row*DD))[t];
  float s  = xv.x+xv.y+xv.z+xv.w;
  float ss = xv.x*xv.x+xv.y*xv.y+xv.z*xv.z+xv.w*xv.w;
  __shared__ float rs[256], rss[256];
  rs[t]=s; rss[t]=ss; __syncthreads();
  for (int st=128; st>0; st>>=1){ if (t<st){ rs[t]+=rs[t+st]; rss[t]+=rss[t+st]; } __syncthreads(); }
  float mean = rs[0] * (1.0f/DD);
  float var  = rss[0]*(1.0f/DD) - mean*mean;
  float inv  = rsqrtf(var + 1e-5f);
  float4 gv = ((const float4*)g)[t], bv = ((const float4*)b)[t];
  ushort4 ov;
  ov.x = f2bu((xv.x-mean)*inv*gv.x + bv.x);
  ov.y = f2bu((xv.y-mean)*inv*gv.y + bv.y);
  ov.z = f2bu((xv.z-mean)*inv*gv.z + bv.z);
  ov.w = f2bu((xv.w-mean)*inv*gv.w + bv.w);
  ((ushort4*)(y + row*DD))[t] = ov;
  // fused kprep: fill Kh rows 512..575 (first 256 blocks, 1 elem/thread)
  int gg = blockIdx.x*256 + t;
  if (gg < 8*64*128) {
    int d = gg & 127, rr = (gg >> 7) & 63, hh = gg >> 13;
    float v = 0.f;
    if (rr < 50) v = embk[rr*128 + d];
    else if (rr < 62) {
      int u = rr - 50; int tb = u/3, f = u - tb*3;
      const float* tab = (tb==0) ? lqc : (tb==1) ? lqt : (tb==2) ? lcq : ltq;
      v = tab[f*128 + d];
    }
    Kh[(((size_t)hh*16 + (d>>3))*KLD + 512 + rr)*8 + (d&7)] = f2bu(v);
  }
}

// ---------------- LayerNorm + out += b2 (split-K init) ----------------
__global__ __launch_bounds__(256) void ln_bf16_addb_kernel(float* __restrict__ x,
    const float* __restrict__ g, const float* __restrict__ b,
    const float* __restrict__ b2, unsigned short* __restrict__ y)
{
  int row = blockIdx.x, t = threadIdx.x;
  const float4 xv = ((const float4*)(x + row*DD))[t];
  float s  = xv.x+xv.y+xv.z+xv.w;
  float ss = xv.x*xv.x+xv.y*xv.y+xv.z*xv.z+xv.w*xv.w;
  __shared__ float rs[256], rss[256];
  rs[t]=s; rss[t]=ss; __syncthreads();
  for (int st=128; st>0; st>>=1){ if (t<st){ rs[t]+=rs[t+st]; rss[t]+=rss[t+st]; } __syncthreads(); }
  float mean = rs[0] * (1.0f/DD);
  float var  = rss[0]*(1.0f/DD) - mean*mean;
  float inv  = rsqrtf(var + 1e-5f);
  float4 gv = ((const float4*)g)[t], bv = ((const float4*)b)[t];
  ushort4 ov;
  ov.x = f2bu((xv.x-mean)*inv*gv.x + bv.x);
  ov.y = f2bu((xv.y-mean)*inv*gv.y + bv.y);
  ov.z = f2bu((xv.z-mean)*inv*gv.z + bv.z);
  ov.w = f2bu((xv.w-mean)*inv*gv.w + bv.w);
  ((ushort4*)(y + row*DD))[t] = ov;
  float4 b2v = ((const float4*)b2)[t];
  float4 nx; nx.x = xv.x+b2v.x; nx.y = xv.y+b2v.y; nx.z = xv.z+b2v.z; nx.w = xv.w+b2v.w;
  ((float4*)(x + row*DD))[t] = nx;
}

// ======== VGPR-staged pipelined bf16 MFMA GEMM; DEPTH = prefetch depth ======
template<int BN, int DEPTH, int CONVB, int ZK, int OUT_BF16, int RELU, int HAS_SRC, int HAS_BIAS>
__global__ __launch_bounds__(256) void gemm_pl(
    const unsigned short* __restrict__ A, int lda, size_t sAz,
    const void* __restrict__ Bv, int ldb, size_t sBz,
    const float* __restrict__ bias,
    const float* __restrict__ src, int ldsrc, size_t sSz,
    void* __restrict__ Cv, int ldc, size_t sCz,
    int K)
{
  constexpr int BM = 64;
  constexpr int WM = 32, WN = BN/2, FM = 2, FN = WN/16;
  constexpr int NB = BN/32;
  constexpr int ABYTES = BM*128, TILE = ABYTES + BN*128;
  __shared__ char lds[2*TILE];
  int t = threadIdx.x, w = t >> 6, l = t & 63;
  size_t z = blockIdx.z;
  const unsigned short* Az = A + z*sAz;
  const unsigned short* Bz16 = (const unsigned short*)Bv + (CONVB ? 0 : z*sBz);
  const float*          Bz32 = (const float*)Bv + (CONVB ? z*sBz : 0);
  int bm = blockIdx.y*BM, bn = blockIdx.x*BN;
  int bnb = bn;
  int wm = (w>>1)*WM, wn = (w&1)*WN;

  float4v acc[FM][FN];
  #pragma unroll
  for (int m=0;m<FM;++m)
    #pragma unroll
    for (int n=0;n<FN;++n) acc[m][n] = (float4v){0.f,0.f,0.f,0.f};

  int r = t >> 3, sl = t & 7;
  int gc = sl ^ (r & 7);
  int quad = l >> 4, lrow = l & 15;
  const int nit = K >> 6;   // DEPTH==2: nit even; DEPTH==4: nit % 4 == 0

  int4 Aa0, Aa1, Ab0, Ab1;  float4 Af0, Af1, Af2, Af3;
  int4 Ba0, Ba1, Bb0, Bb1;  float4 Bf0, Bf1, Bf2, Bf3;
  int4 Ca0, Ca1, Cb0, Cb1;  float4 Cf0, Cf1, Cf2, Cf3;
  int4 Da0, Da1, Db0, Db1;  float4 Df0, Df1, Df2, Df3;

  auto compute = [&](const char* base) {
    const char* ab = base;
    const char* bb = base + ABYTES;
    #pragma unroll
    for (int step=0; step<2; ++step) {
      int c = step*4 + quad;
      short8 af[FM], bf[FN];
      #pragma unroll
      for (int m=0;m<FM;++m) {
        int Rw = wm + m*16 + lrow;
        af[m] = *(const short8*)(ab + Rw*128 + ((c ^ (Rw & 7))*16));
      }
      #pragma unroll
      for (int n=0;n<FN;++n) {
        int Rw = wn + n*16 + lrow;
        bf[n] = *(const short8*)(bb + Rw*128 + ((c ^ (Rw & 7))*16));
      }
      #pragma unroll
      for (int m=0;m<FM;++m)
        #pragma unroll
        for (int n=0;n<FN;++n)
          acc[m][n] = __builtin_amdgcn_mfma_f32_16x16x32_bf16(af[m], bf[n], acc[m][n], 0, 0, 0);
    }
  };

  if constexpr (DEPTH == 2) {
    LOADSET(Aa0,Aa1,Ab0,Ab1,Af0,Af1,Af2,Af3, 0);
    LOADSET(Ba0,Ba1,Bb0,Bb1,Bf0,Bf1,Bf2,Bf3, 1);
    for (int it = 0; it < nit; it += 2) {
      STORESET2(lds, Aa0,Aa1,Ab0,Ab1,Af0,Af1,Af2,Af3);
      if (it + 2 < nit) LOADSET(Aa0,Aa1,Ab0,Ab1,Af0,Af1,Af2,Af3, it+2);
      lds_barrier();
      compute(lds);
      STORESET2(lds + TILE, Ba0,Ba1,Bb0,Bb1,Bf0,Bf1,Bf2,Bf3);
      if (it + 3 < nit) LOADSET(Ba0,Ba1,Bb0,Bb1,Bf0,Bf1,Bf2,Bf3, it+3);
      lds_barrier();
      compute(lds + TILE);
    }
  } else {
    LOADSET(Aa0,Aa1,Ab0,Ab1,Af0,Af1,Af2,Af3, 0);
    LOADSET(Ba0,Ba1,Bb0,Bb1,Bf0,Bf1,Bf2,Bf3, 1);
    LOADSET(Ca0,Ca1,Cb0,Cb1,Cf0,Cf1,Cf2,Cf3, 2);
    LOADSET(Da0,Da1,Db0,Db1,Df0,Df1,Df2,Df3, 3);
    for (int it = 0; it < nit; it += 4) {
      STORESET2(lds, Aa0,Aa1,Ab0,Ab1,Af0,Af1,Af2,Af3);
      if (it + 4 < nit) LOADSET(Aa0,Aa1,Ab0,Ab1,Af0,Af1,Af2,Af3, it+4);
      lds_barrier();
      compute(lds);
      STORESET2(lds + TILE, Ba0,Ba1,Bb0,Bb1,Bf0,Bf1,Bf2,Bf3);
      if (it + 5 < nit) LOADSET(Ba0,Ba1,Bb0,Bb1,Bf0,Bf1,Bf2,Bf3, it+5);
      lds_barrier();
      compute(lds + TILE);
      STORESET2(lds, Ca0,Ca1,Cb0,Cb1,Cf0,Cf1,Cf2,Cf3);
      if (it + 6 < nit) LOADSET(Ca0,Ca1,Cb0,Cb1,Cf0,Cf1,Cf2,Cf3, it+6);
      lds_barrier();
      compute(lds);
      STORESET2(lds + TILE, Da0,Da1,Db0,Db1,Df0,Df1,Df2,Df3);
      if (it + 7 < nit) LOADSET(Da0,Da1,Db0,Db1,Df0,Df1,Df2,Df3, it+7);
      lds_barrier();
      compute(lds + TILE);
    }
  }

  #pragma unroll
  for (int m=0;m<FM;++m)
    #pragma unroll
    for (int n=0;n<FN;++n)
      #pragma unroll
      for (int rg=0;rg<4;++rg) {
        int row = bm + wm + m*16 + quad*4 + rg;
        int col = bn + wn + n*16 + lrow;
        float vv = acc[m][n][rg];
        if (ZK) {
          atomicAdd(&((float*)Cv)[(size_t)row*ldc + col], vv);
        } else {
          if (HAS_BIAS) vv += bias[col];
          if (HAS_SRC)  vv += src[z*sSz + (size_t)row*ldsrc + col];
          if (RELU) vv = fmaxf(vv, 0.f);
          if (OUT_BF16) ((unsigned short*)Cv)[z*sCz + (size_t)row*ldc + col] = f2bu(vv);
          else          ((float*)Cv)[z*sCz + (size_t)row*ldc + col] = vv;
        }
      }
}

// ======== 8-wave BM=128 pipelined GEMM (512 thr, 4M x 2N waves, DEPTH 4) ====
template<int BN, int CONVB, int ZK, int OUT_BF16, int RELU, int HAS_SRC, int HAS_BIAS>
__global__ __launch_bounds__(512) void gemm_pl8(
    const unsigned short* __restrict__ A, int lda, size_t sAz,
    const void* __restrict__ Bv, int ldb, size_t sBz,
    const float* __restrict__ bias,
    const float* __restrict__ src, int ldsrc, size_t sSz,
    void* __restrict__ Cv, int ldc, size_t sCz,
    int K)
{
  constexpr int BM = 128;
  constexpr int FM = 2, FN = 2;
  constexpr int ABYTES = BM*128, TILE = ABYTES + BN*128;   // BN==64
  __shared__ char lds[2*TILE];
  int t = threadIdx.x, w = t >> 6, l = t & 63;
  size_t z = blockIdx.z;
  const unsigned short* Az = A + z*sAz;
  const unsigned short* Bz16 = (const unsigned short*)Bv + (CONVB ? 0 : z*sBz);
  const float*          Bz32 = (const float*)Bv + (CONVB ? z*sBz : 0);
  int bm = blockIdx.y*BM, bn = blockIdx.x*BN;
  int bnb = bn;
  int wm = (w>>1)*32, wn = (w&1)*32;

  float4v acc[FM][FN];
  #pragma unroll
  for (int m=0;m<FM;++m)
    #pragma unroll
    for (int n=0;n<FN;++n) acc[m][n] = (float4v){0.f,0.f,0.f,0.f};

  int r = t >> 3, sl = t & 7;      // r in 0..63
  int gc = sl ^ (r & 7);
  int quad = l >> 4, lrow = l & 15;
  const int nit = K >> 6;          // multiple of 4

  int4 Aa0, Aa1, Ab0;  float4 Af0, Af1;
  int4 Ba0, Ba1, Bb0;  float4 Bf0, Bf1;
  int4 Ca0, Ca1, Cb0;  float4 Cf0, Cf1;
  int4 Da0, Da1, Db0;  float4 Df0, Df1;

  auto compute = [&](const char* base) {
    const char* ab = base;
    const char* bb = base + ABYTES;
    #pragma unroll
    for (int step=0; step<2; ++step) {
      int c = step*4 + quad;
      short8 af[FM], bf[FN];
      #pragma unroll
      for (int m=0;m<FM;++m) {
        int Rw = wm + m*16 + lrow;
        af[m] = *(const short8*)(ab + Rw*128 + ((c ^ (Rw & 7))*16));
      }
      #pragma unroll
      for (int n=0;n<FN;++n) {
        int Rw = wn + n*16 + lrow;
        bf[n] = *(const short8*)(bb + Rw*128 + ((c ^ (Rw & 7))*16));
      }
      #pragma unroll
      for (int m=0;m<FM;++m)
        #pragma unroll
        for (int n=0;n<FN;++n)
          acc[m][n] = __builtin_amdgcn_mfma_f32_16x16x32_bf16(af[m], bf[n], acc[m][n], 0, 0, 0);
    }
  };

  LOADSET8(Aa0,Aa1,Ab0,Af0,Af1, 0);
  LOADSET8(Ba0,Ba1,Bb0,Bf0,Bf1, 1);
  LOADSET8(Ca0,Ca1,Cb0,Cf0,Cf1, 2);
  LOADSET8(Da0,Da1,Db0,Df0,Df1, 3);
  for (int it = 0; it < nit; it += 4) {
    STORESET8(lds, Aa0,Aa1,Ab0,Af0,Af1);
    if (it + 4 < nit) LOADSET8(Aa0,Aa1,Ab0,Af0,Af1, it+4);
    lds_barrier();
    compute(lds);
    STORESET8(lds + TILE, Ba0,Ba1,Bb0,Bf0,Bf1);
    if (it + 5 < nit) LOADSET8(Ba0,Ba1,Bb0,Bf0,Bf1, it+5);
    lds_barrier();
    compute(lds + TILE);
    STORESET8(lds, Ca0,Ca1,Cb0,Cf0,Cf1);
    if (it + 6 < nit) LOADSET8(Ca0,Ca1,Cb0,Cf0,Cf1, it+6);
    lds_barrier();
    compute(lds);
    STORESET8(lds + TILE, Da0,Da1,Db0,Df0,Df1);
    if (it + 7 < nit) LOADSET8(Da0,Da1,Db0,Df0,Df1, it+7);
    lds_barrier();
    compute(lds + TILE);
  }

  #pragma unroll
  for (int m=0;m<FM;++m)
    #pragma unroll
    for (int n=0;n<FN;++n)
      #pragma unroll
      for (int rg=0;rg<4;++rg) {
        int row = bm + wm + m*16 + quad*4 + rg;
        int col = bn + wn + n*16 + lrow;
        float vv = acc[m][n][rg];
        if (ZK) {
          atomicAdd(&((float*)Cv)[(size_t)row*ldc + col], vv);
        } else {
          if (HAS_BIAS) vv += bias[col];
          if (HAS_SRC)  vv += src[z*sSz + (size_t)row*ldsrc + col];
          if (RELU) vv = fmaxf(vv, 0.f);
          if (OUT_BF16) ((unsigned short*)Cv)[z*sCz + (size_t)row*ldc + col] = f2bu(vv);
          else          ((float*)Cv)[z*sCz + (size_t)row*ldc + col] = vv;
        }
      }
}

// ------ QKV GEMM 8-wave: fp32 weights direct, BM=128, head-scatter ---------
__global__ __launch_bounds__(512) void gemm_qkv_pl8(
    const unsigned short* __restrict__ A,
    const float* __restrict__ Wq, const float* __restrict__ Wk,
    const float* __restrict__ Wv,
    const float* __restrict__ bq, const float* __restrict__ bk,
    const float* __restrict__ bv,
    unsigned short* __restrict__ Qh, unsigned short* __restrict__ Kh,
    unsigned short* __restrict__ Vt)
{
  constexpr int BN = 64, CONVB = 1;
  constexpr int FM = 2, FN = 2;
  constexpr int ABYTES = 128*128, TILE = ABYTES + BN*128;
  __shared__ char lds[2*TILE];
  int t = threadIdx.x, w = t >> 6, l = t & 63;
  int bm = blockIdx.y*128, bn = blockIdx.x*BN;
  int wm = (w>>1)*32, wn = (w&1)*32;
  const int lda = DD, ldb = DD, nit = DD >> 6;   // 16
  const unsigned short* Az = A;
  int part0 = bn >> 10;
  const float* Bz32 = (part0==0 ? Wq : part0==1 ? Wk : Wv) + (size_t)(bn & 1023)*DD;
  const unsigned short* Bz16 = nullptr; (void)Bz16;
  int bnb = 0;

  float4v acc[FM][FN];
  #pragma unroll
  for (int m=0;m<FM;++m)
    #pragma unroll
    for (int n=0;n<FN;++n) acc[m][n] = (float4v){0.f,0.f,0.f,0.f};

  int r = t >> 3, sl = t & 7;
  int gc = sl ^ (r & 7);
  int quad = l >> 4, lrow = l & 15;

  int4 Aa0, Aa1, Ab0;  float4 Af0, Af1;
  int4 Ba0, Ba1, Bb0;  float4 Bf0, Bf1;
  int4 Ca0, Ca1, Cb0;  float4 Cf0, Cf1;
  int4 Da0, Da1, Db0;  float4 Df0, Df1;

  auto compute = [&](const char* base) {
    const char* ab = base;
    const char* bb = base + ABYTES;
    #pragma unroll
    for (int step=0; step<2; ++step) {
      int c = step*4 + quad;
      short8 af[FM], bf[FN];
      #pragma unroll
      for (int m=0;m<FM;++m) {
        int Rw = wm + m*16 + lrow;
        af[m] = *(const short8*)(ab + Rw*128 + ((c ^ (Rw & 7))*16));
      }
      #pragma unroll
      for (int n=0;n<FN;++n) {
        int Rw = wn + n*16 + lrow;
        bf[n] = *(const short8*)(bb + Rw*128 + ((c ^ (Rw & 7))*16));
      }
      #pragma unroll
      for (int m=0;m<FM;++m)
        #pragma unroll
        for (int n=0;n<FN;++n)
          acc[m][n] = __builtin_amdgcn_mfma_f32_16x16x32_bf16(af[m], bf[n], acc[m][n], 0, 0, 0);
    }
  };

  LOADSET8(Aa0,Aa1,Ab0,Af0,Af1, 0);
  LOADSET8(Ba0,Ba1,Bb0,Bf0,Bf1, 1);
  LOADSET8(Ca0,Ca1,Cb0,Cf0,Cf1, 2);
  LOADSET8(Da0,Da1,Db0,Df0,Df1, 3);
  for (int it = 0; it < nit; it += 4) {
    STORESET8(lds, Aa0,Aa1,Ab0,Af0,Af1);
    if (it + 4 < nit) LOADSET8(Aa0,Aa1,Ab0,Af0,Af1, it+4);
    lds_barrier();
    compute(lds);
    STORESET8(lds + TILE, Ba0,Ba1,Bb0,Bf0,Bf1);
    if (it + 5 < nit) LOADSET8(Ba0,Ba1,Bb0,Bf0,Bf1, it+5);
    lds_barrier();
    compute(lds + TILE);
    STORESET8(lds, Ca0,Ca1,Cb0,Cf0,Cf1);
    if (it + 6 < nit) LOADSET8(Ca0,Ca1,Cb0,Cf0,Cf1, it+6);
    lds_barrier();
    compute(lds);
    STORESET8(lds + TILE, Da0,Da1,Db0,Df0,Df1);
    if (it + 7 < nit) LOADSET8(Da0,Da1,Db0,Df0,Df1, it+7);
    lds_barrier();
    compute(lds + TILE);
  }

  #pragma unroll
  for (int m=0;m<FM;++m)
    #pragma unroll
    for (int n=0;n<FN;++n)
      #pragma unroll
      for (int rg=0;rg<4;++rg) {
        int row = bm + wm + m*16 + quad*4 + rg;
        int col = bn + wn + n*16 + lrow;
        int part = col >> 10, hh = (col >> 7) & 7, d = col & 127;
        const float* bp = (part==0) ? bq : (part==1) ? bk : bv;
        float vv = acc[m][n][rg] + bp[col & 1023];
        unsigned short o = f2bu(vv);
        if (part == 0)      Qh[((size_t)hh*LL + row)*DKK + d] = o;
        else if (part == 1) Kh[(((size_t)hh*16 + (d>>3))*KLD + row)*8 + (d&7)] = o;
        else                Vt[(((size_t)hh*64 + (row>>3))*128 + d)*8 + (row&7)] = o;
      }
}

// ======== fused attention v3: direct-global K/V MFMA operands, 4 barriers ====
// grid (64,8), 256 thr. K/V in slice-major layout -> B-fragments load coalesced
// straight from L2; no K/V LDS staging at all.
// LDS map (bytes):
//   [0    , 2176 )  Qt   [8][136]  bf16 (stride 272)
//   [2176 , 10496)  P    [8][520]  bf16 (stride 1040)
//   [10496, 29184)  S    [8][584]  f32  (stride 2336 B)
//   [29184, 30848)  pws  [8][52]   f32
//   [30848, 30976)  pf1  [8][4]    f32
//   [30976, 31104)  pf2  [8][4]    f32
//   [31104, 31136)  sinv [8]       f32
//   [31136, 35360)  o2s  [8][132]  f32
#define A3_QROWB 272
#define A3_PROWB 1040
#define A3_SROWD 584
#define A3_O2ROW 132
#define A3_OFF_P   2176
#define A3_OFF_S   10496
#define A3_OFF_PW  29184
#define A3_OFF_PF1 30848
#define A3_OFF_PF2 30976
#define A3_OFF_SI  31104
#define A3_OFF_O2  31136
#define A3_LDS     35360

__global__ __launch_bounds__(256) void attn_fused(
    const unsigned short* __restrict__ Qh, const unsigned short* __restrict__ Kh,
    const unsigned short* __restrict__ Vt,
    const float* __restrict__ qcr, const float* __restrict__ cqr,
    const float* __restrict__ qtr, const float* __restrict__ tqr,
    const int* __restrict__ ct, const int* __restrict__ pred,
    const int* __restrict__ mask,
    const float* __restrict__ embv, const float* __restrict__ lqc_v,
    const float* __restrict__ lcq_v, const float* __restrict__ lqt_v,
    const float* __restrict__ ltq_v,
    unsigned short* __restrict__ obuf)
{
  __shared__ __align__(16) char lds[A3_LDS];
  const int t = threadIdx.x;
  const int w = t >> 6, l = t & 63, quad = l >> 4, lrow = l & 15;
  const int i0 = blockIdx.x * 8, h = blockIdx.y;

  // zero pws/pf/sinv region (488 floats)
  for (int k2 = t; k2 < 488; k2 += 256) ((float*)(lds + A3_OFF_PW))[k2] = 0.f;

  // stage Q tile [8][128]
  if (t < 128) {
    int qr = t >> 4, qc = t & 15;
    *(int4*)(lds + qr*A3_QROWB + qc*16) =
        *(const int4*)(Qh + ((size_t)h*LL + i0 + qr)*DKK + qc*8);
  }
  lds_barrier();    // barrier 1: Qt + zeroed pws visible

  // ---- phase 1: S[8][576] = Q @ Kh^T, K fragments direct from global ----
  {
    const unsigned short* Kc = Kh + (size_t)h*16*KLD*8;
    short8 af0 = *(const short8*)(lds + lrow*A3_QROWB + (quad     )*16);
    short8 af1 = *(const short8*)(lds + lrow*A3_QROWB + (quad +  4)*16);
    short8 af2 = *(const short8*)(lds + lrow*A3_QROWB + (quad +  8)*16);
    short8 af3 = *(const short8*)(lds + lrow*A3_QROWB + (quad + 12)*16);
    #pragma unroll
    for (int jt = 0; jt < 9; ++jt) {
      float4v acc = (float4v){0.f,0.f,0.f,0.f};
      int krow = jt*64 + w*16 + lrow;
      short8 bf0 = *(const short8*)(Kc + ((size_t)(quad     )*KLD + krow)*8);
      short8 bf1 = *(const short8*)(Kc + ((size_t)(quad +  4)*KLD + krow)*8);
      short8 bf2 = *(const short8*)(Kc + ((size_t)(quad +  8)*KLD + krow)*8);
      short8 bf3 = *(const short8*)(Kc + ((size_t)(quad + 12)*KLD + krow)*8);
      acc = __builtin_amdgcn_mfma_f32_16x16x32_bf16(af0, bf0, acc, 0, 0, 0);
      acc = __builtin_amdgcn_mfma_f32_16x16x32_bf16(af1, bf1, acc, 0, 0, 0);
      acc = __builtin_amdgcn_mfma_f32_16x16x32_bf16(af2, bf2, acc, 0, 0, 0);
      acc = __builtin_amdgcn_mfma_f32_16x16x32_bf16(af3, bf3, acc, 0, 0, 0);
      if (quad < 2) {
        #pragma unroll
        for (int rg = 0; rg < 4; ++rg)
          ((float*)(lds + A3_OFF_S))[(quad*4 + rg)*A3_SROWD + jt*64 + w*16 + lrow] = acc[rg];
      }
    }
  }
  lds_barrier();    // barrier 2: S visible

  // ---- phase 2: single-pass unnormalized softmax (32 lanes per row) ----
  const int row = t >> 5, l32 = t & 31;
  const int i = i0 + row;
  const float* Sp = (const float*)(lds + A3_OFF_S) + row*A3_SROWD;
  const int bse = (i0 < QQ) ? 562 : (i0 < QQ + CCC) ? 568 : 571;
  const float lq1a = Sp[bse], lq1b = Sp[bse+1], lq1c = Sp[bse+2];
  const float lq2a = Sp[565], lq2b = Sp[566], lq2c = Sp[567];

  float sum=0.f, f0=0.f, f1=0.f, f2=0.f, g0=0.f, g1=0.f, g2=0.f;
  float* pwsrow = (float*)(lds + A3_OFF_PW) + row*52;
  #pragma unroll
  for (int m = 0; m < 16; ++m) {
    int j = m*32 + l32;
    int predv = pred[i*LL + j];
    int maskv = mask[i*LL + j];
    float s = Sp[j] + Sp[512 + predv];
    float c0=0.f, c1=0.f, c2=0.f; int rt; int scat2 = 0;
    if (i0 < QQ) {
      if (j < QQ) { s += Sp[512]; rt = 0; }
      else if (j < QQ + CCC) {
        const float* r3 = qcr + ((size_t)i*CCC + (j - QQ))*3;
        c0 = r3[0]; c1 = r3[1]; c2 = r3[2];
        s += c0*lq1a + c1*lq1b + c2*lq1c; rt = 1;
      } else {
        const float* r3 = qtr + ((size_t)i*TTT + (j - QQ - CCC))*3;
        c0 = r3[0]; c1 = r3[1]; c2 = r3[2];
        s += c0*lq2a + c1*lq2b + c2*lq2c; rt = 2;
      }
    } else {
      if (j < QQ) {
        const float* r3 = (i < QQ + CCC) ? cqr + ((size_t)(i - QQ)*QQ + j)*3
                                         : tqr + ((size_t)(i - QQ - CCC)*QQ + j)*3;
        c0 = r3[0]; c1 = r3[1]; c2 = r3[2];
        s += c0*lq1a + c1*lq1b + c2*lq1c; rt = 1;
      } else {
        scat2 = ct[(i - QQ)*(CCC + TTT) + (j - QQ)];
        s += Sp[512 + scat2]; rt = 0;
      }
    }
    s *= 0.08838834764831845f;
    float e = (maskv == 0) ? 0.f : __expf(s);
    sum += e;
    *(unsigned short*)(lds + A3_OFF_P + row*A3_PROWB + j*2) = f2bu(e);
    atomicAdd(pwsrow + predv, e);
    if (rt == 0)      atomicAdd(pwsrow + scat2, e);
    else if (rt == 1) { f0 += e*c0; f1 += e*c1; f2 += e*c2; }
    else              { g0 += e*c0; g1 += e*c1; g2 += e*c2; }
  }
  #pragma unroll
  for (int off = 16; off >= 1; off >>= 1) {
    sum += __shfl_xor(sum, off);
    f0 += __shfl_xor(f0, off); f1 += __shfl_xor(f1, off); f2 += __shfl_xor(f2, off);
    g0 += __shfl_xor(g0, off); g1 += __shfl_xor(g1, off); g2 += __shfl_xor(g2, off);
  }
  if (l32 == 0) {
    float* pf1 = (float*)(lds + A3_OFF_PF1) + row*4;
    float* pf2 = (float*)(lds + A3_OFF_PF2) + row*4;
    pf1[0] = f0; pf1[1] = f1; pf1[2] = f2;
    pf2[0] = g0; pf2[1] = g1; pf2[2] = g2;
    ((float*)(lds + A3_OFF_SI))[row] = 1.0f / sum;
  }
  lds_barrier();    // barrier 3: P/pws/pf/sinv visible; S reads done

  // ---- o2term: o2s[row][d] = pws@embv + pf@tables (f32), per-thread (row,d) ----
  {
    int orow = t >> 5, d0 = (t & 31)*4;
    const float* pwsr = (const float*)(lds + A3_OFF_PW) + orow*52;
    float a0=0.f, a1=0.f, a2=0.f, a3=0.f;
    #pragma unroll 5
    for (int rr = 0; rr < RR; ++rr) {
      float pv = pwsr[rr];
      float4 ev = *(const float4*)(embv + rr*DKK + d0);
      a0 += pv*ev.x; a1 += pv*ev.y; a2 += pv*ev.z; a3 += pv*ev.w;
    }
    const float* tab1 = (i0 < QQ) ? lqc_v : (i0 < QQ + CCC) ? lcq_v : ltq_v;
    const float* pf1 = (const float*)(lds + A3_OFF_PF1) + orow*4;
    float4 t0 = *(const float4*)(tab1 + d0);
    float4 t1 = *(const float4*)(tab1 + DKK + d0);
    float4 t2 = *(const float4*)(tab1 + 2*DKK + d0);
    a0 += pf1[0]*t0.x + pf1[1]*t1.x + pf1[2]*t2.x;
    a1 += pf1[0]*t0.y + pf1[1]*t1.y + pf1[2]*t2.y;
    a2 += pf1[0]*t0.z + pf1[1]*t1.z + pf1[2]*t2.z;
    a3 += pf1[0]*t0.w + pf1[1]*t1.w + pf1[2]*t2.w;
    if (i0 < QQ) {
      const float* pf2 = (const float*)(lds + A3_OFF_PF2) + orow*4;
      float4 u0 = *(const float4*)(lqt_v + d0);
      float4 u1 = *(const float4*)(lqt_v + DKK + d0);
      float4 u2 = *(const float4*)(lqt_v + 2*DKK + d0);
      a0 += pf2[0]*u0.x + pf2[1]*u1.x + pf2[2]*u2.x;
      a1 += pf2[0]*u0.y + pf2[1]*u1.y + pf2[2]*u2.y;
      a2 += pf2[0]*u0.z + pf2[1]*u1.z + pf2[2]*u2.z;
      a3 += pf2[0]*u0.w + pf2[1]*u1.w + pf2[2]*u2.w;
    }
    float4 av; av.x=a0; av.y=a1; av.z=a2; av.w=a3;
    *(float4*)((float*)(lds + A3_OFF_O2) + orow*A3_O2ROW + d0) = av;
  }
  lds_barrier();    // barrier 4: o2s visible

  // ---- phase 3: O[8][128] = E @ V^T, V fragments direct from global; no barriers ----
  float4v oacc0 = (float4v){0.f,0.f,0.f,0.f};
  float4v oacc1 = (float4v){0.f,0.f,0.f,0.f};
  {
    const unsigned short* Vc = Vt + (size_t)h*64*128*8;
    #pragma unroll
    for (int it = 0; it < 8; ++it) {
      #pragma unroll
      for (int kk = 0; kk < 2; ++kk) {
        int c = kk*4 + quad;
        short8 pa  = *(const short8*)(lds + A3_OFF_P + lrow*A3_PROWB + it*128 + c*16);
        short8 vf0 = *(const short8*)(Vc + (((size_t)(it*8 + c))*128 + w*32 + lrow)*8);
        short8 vf1 = *(const short8*)(Vc + (((size_t)(it*8 + c))*128 + w*32 + 16 + lrow)*8);
        oacc0 = __builtin_amdgcn_mfma_f32_16x16x32_bf16(pa, vf0, oacc0, 0, 0, 0);
        oacc1 = __builtin_amdgcn_mfma_f32_16x16x32_bf16(pa, vf1, oacc1, 0, 0, 0);
      }
    }
  }

  // ---- epilogue: (oacc + o2s) * sinv -> obuf bf16 ----
  if (quad < 2) {
    const float* o2s = (const float*)(lds + A3_OFF_O2);
    const float* sinv = (const float*)(lds + A3_OFF_SI);
    #pragma unroll
    for (int n = 0; n < 2; ++n) {
      int d = w*32 + n*16 + lrow;
      #pragma unroll
      for (int rg = 0; rg < 4; ++rg) {
        int rw = quad*4 + rg;
        float oval = (n==0) ? oacc0[rg] : oacc1[rg];
        float val = (oval + o2s[rw*A3_O2ROW + d]) * sinv[rw];
        obuf[(size_t)(i0 + rw)*DD + h*DKK + d] = f2bu(val);
      }
    }
  }
}

// ---------------- launch ----------------
extern "C" void kernel_launch(void* const* d_in, const int* in_sizes, int n_in,
                              void* d_out, int out_size, void* d_ws, size_t ws_size,
                              hipStream_t stream)
{
  const float* x    = (const float*)d_in[0];
  const float* qcr  = (const float*)d_in[1];
  const float* cqr  = (const float*)d_in[2];
  const float* qtr  = (const float*)d_in[3];
  const float* tqr  = (const float*)d_in[4];
  const int*   ct   = (const int*)d_in[5];
  const int*   pred = (const int*)d_in[6];
  const int*   mask = (const int*)d_in[7];
  const float* embk = (const float*)d_in[8];
  const float* embv = (const float*)d_in[9];
  const float* lqc_k = (const float*)d_in[10];
  const float* lqc_v = (const float*)d_in[11];
  const float* lcq_k = (const float*)d_in[12];
  const float* lcq_v = (const float*)d_in[13];
  const float* lqt_k = (const float*)d_in[14];
  const float* lqt_v = (const float*)d_in[15];
  const float* ltq_k = (const float*)d_in[16];
  const float* ltq_v = (const float*)d_in[17];
  const float* Wq = (const float*)d_in[18]; const float* bq = (const float*)d_in[19];
  const float* Wk = (const float*)d_in[20]; const float* bk = (const float*)d_in[21];
  const float* Wv = (const float*)d_in[22]; const float* bv = (const float*)d_in[23];
  const float* Wo = (const float*)d_in[24]; const float* bo = (const float*)d_in[25];
  const float* ln1_g = (const float*)d_in[26]; const float* ln1_b = (const float*)d_in[27];
  const float* ln2_g = (const float*)d_in[28]; const float* ln2_b = (const float*)d_in[29];
  const float* W1 = (const float*)d_in[30]; const float* b1 = (const float*)d_in[31];
  const float* W2 = (const float*)d_in[32]; const float* b2 = (const float*)d_in[33];
  float* out = (float*)d_out;

  float* wsf = (float*)d_ws;
  float* S    = wsf;                          // FFN hidden region (attention no longer uses it)
  float* o2   = S + (size_t)HH*LL*SLD;        // kept for layout stability (unused)
  unsigned short* ub = (unsigned short*)(o2 + (size_t)HH*LL*DKK);
  unsigned short* ybuf_b = ub;                        // [L,D]
  unsigned short* obuf_b = ybuf_b + LL*DD;            // [L,D]
  unsigned short* Qh     = obuf_b + LL*DD;            // [H][512][128]
  unsigned short* Kh     = Qh + (size_t)HH*LL*DKK;    // [H][16][576][8] slice-major
  unsigned short* Vt     = Kh + (size_t)HH*KLD*DKK;   // [H][64][128][8] slice-major
  unsigned short* hidden = (unsigned short*)S;        // [L][FFF] bf16

  // 1. LN1 -> bf16 (+ fused kprep: Kh rows 512..575)
  ln_bf16_kernel<<<LL, 256, 0, stream>>>(x, ln1_g, ln1_b, ybuf_b,
                                         embk, lqc_k, lqt_k, lcq_k, ltq_k, Kh);
  // 2. QKV GEMM (8-wave BM=128, fp32 weights direct) with head scatter
  gemm_qkv_pl8<<<dim3(48, 4), 512, 0, stream>>>(ybuf_b, Wq, Wk, Wv, bq, bk, bv,
                                                Qh, Kh, Vt);
  // 3. fused attention v3: direct-global K/V, 4 barriers
  attn_fused<<<dim3(64, 8), 256, 0, stream>>>(
      Qh, Kh, Vt, qcr, cqr, qtr, tqr, ct, pred, mask,
      embv, lqc_v, lcq_v, lqt_v, ltq_v, obuf_b);
  // 4. out-proj (fp32 Wo direct, depth-4) + residual(x) -> out
  gemm_pl<32,4,1,0,0,0,1,1><<<dim3(32, 8, 1), 256, 0, stream>>>(
      obuf_b, DD, 0, Wo, DD, 0, bo, x, DD, 0, out, DD, 0, DD);
  // 5. LN2 -> bf16, and out += b2 (split-K init)
  ln_bf16_addb_kernel<<<LL, 256, 0, stream>>>(out, ln2_g, ln2_b, b2, ybuf_b);
  // 6. FFN1 relu (8-wave BM=128, fp32 W1 direct) -> hidden bf16
  gemm_pl8<64,1,0,1,1,0,1><<<dim3(64, 4), 512, 0, stream>>>(
      ybuf_b, DD, 0, W1, DD, 0, b1, nullptr, 0, 0, hidden, FFF, 0, DD);
  // 7. FFN2 split-K x4 (8-wave BM=128, fp32 W2 direct), atomicAdd -> out
  gemm_pl8<64,1,1,0,0,0,0><<<dim3(16, 4, 4), 512, 0, stream>>>(
      hidden, FFF, (size_t)1024, W2, FFF, (size_t)1024,
      nullptr, nullptr, 0, 0, out, DD, 0, 1024);
}